// Round 4
// baseline (951.331 us; speedup 1.0000x reference)
//
#include <hip/hip_runtime.h>
#include <hip/hip_bf16.h>

__device__ __forceinline__ float sigf(float x) {
  return __fdividef(1.0f, 1.0f + __expf(-x));
}
__device__ __forceinline__ float tanhfast(float x) {
  float e = __expf(2.0f * x);
  return 1.0f - __fdividef(2.0f, e + 1.0f);
}

// ---------------------------------------------------------------------------
// K_pre: build permuted weights + transposed tree weights in ws.
//  WhhP[k][u*4+g] = Whh1[k][g*128+u]   (128x512)
//  WihP[d][u*4+g] = Wih1[d][g*128+u]   (13x512)
//  b1P[u*4+g]     = b1[g*128+u]
//  WT[m][k][h]    = (m<5?Wlh:Wrh)[m%5][h][k]
// ---------------------------------------------------------------------------
__global__ __launch_bounds__(256) void k_pre(
    const float* __restrict__ Whh1, const float* __restrict__ Wih1,
    const float* __restrict__ b1, const float* __restrict__ Wlh,
    const float* __restrict__ Wrh,
    float* __restrict__ WhhP, float* __restrict__ WihP,
    float* __restrict__ b1P, float* __restrict__ WT)
{
  const int bx = blockIdx.x, tid = threadIdx.x;
  if (bx < 32) {
    // WhhP: 65536 elems, 2048 per block
    for (int i = 0; i < 8; ++i) {
      int dst = bx * 2048 + i * 256 + tid;
      int g = dst & 3, u = (dst >> 2) & 127, k = dst >> 9;
      WhhP[dst] = Whh1[k * 512 + g * 128 + u];
    }
  } else if (bx == 32) {
    for (int idx = tid; idx < 13 * 512; idx += 256) {
      int g = idx & 3, u = (idx >> 2) & 127, d = idx >> 9;
      WihP[idx] = Wih1[d * 512 + g * 128 + u];
    }
    for (int idx = tid; idx < 512; idx += 256)
      b1P[idx] = b1[(idx & 3) * 128 + (idx >> 2)];
  } else {
    __shared__ float tile[32][33];
    const int m = bx - 33;                 // 0..9 = side*5+g
    const int side = m / 5, g = m - side * 5;
    const float* src = (side ? Wrh : Wlh) + g * 16384;
    float* dst = WT + m * 16384;
    const int i = tid >> 5, jj = tid & 31;  // i in [0,8)
    for (int tt = 0; tt < 16; ++tt) {
      const int ti = tt >> 2, tj = tt & 3;
#pragma unroll
      for (int q = 0; q < 4; ++q)
        tile[i + q * 8][jj] = src[(ti * 32 + i + q * 8) * 128 + tj * 32 + jj];
      __syncthreads();
#pragma unroll
      for (int q = 0; q < 4; ++q)
        dst[(tj * 32 + i + q * 8) * 128 + ti * 32 + jj] = tile[jj][i + q * 8];
      __syncthreads();
    }
  }
}

// ---------------------------------------------------------------------------
// K1: LSTM1, 256 blocks x 256 threads, 16 seqs/block.
// Thread (u = tid&127, rg = tid>>7): 8 rows (8*rg..) x unit u's 4 gate cols
// (permuted layout -> one float4 per k). h-reads are wave-uniform broadcasts.
// Weights: double-buffered 16-row chunks of WhhP via global->reg->LDS.
// Epilogue: relu(h@Wc+bc), lo pairs, per-block BN1 partials -> gpartial.
// ---------------------------------------------------------------------------
__global__ __launch_bounds__(256, 1) void k_lstm1(
    const float* __restrict__ cond1, const float* __restrict__ cond2,
    const float* __restrict__ WihP, const float* __restrict__ WhhP,
    const float* __restrict__ b1P, const float* __restrict__ Wc,
    const float* __restrict__ bc,
    float* __restrict__ lo_raw, float* __restrict__ gpartial)
{
  __shared__ float wS[2][16][512];   // 64KB double-buffered weight chunk
  __shared__ float hs[16][132];
  __shared__ float xs[16][132];
  __shared__ float rr[16][64];
  __shared__ float sloc[128];

  const int tid = threadIdx.x;
  const int b = blockIdx.x;

  for (int idx = tid; idx < 16 * 130; idx += 256) {
    int r = idx / 130, d = idx - r * 130;
    xs[r][d] = (r < 8) ? cond1[(8 * b + r) * 130 + d]
                       : cond2[(8 * b + (r - 8)) * 130 + d];
  }
  for (int idx = tid; idx < 16 * 132; idx += 256) (&hs[0][0])[idx] = 0.0f;
  if (tid < 128) sloc[tid] = 0.0f;

  const int u = tid & 127;
  const int rg = tid >> 7;      // 0..1 -> rows 8rg..8rg+7
  const int row0 = 8 * rg;

  float4 wihv[13];
#pragma unroll
  for (int d = 0; d < 13; ++d)
    wihv[d] = *(const float4*)&WihP[d * 512 + 4 * u];
  const float4 b1v = *(const float4*)&b1P[4 * u];

  float creg[8];
#pragma unroll
  for (int r = 0; r < 8; ++r) creg[r] = 0.0f;

  const float4* wsrc = (const float4*)WhhP;   // 16384 f4; chunk = 2048 f4
  float4 stg[8];
  // prologue: stage chunk 0 into buffer 0
#pragma unroll
  for (int q = 0; q < 8; ++q) stg[q] = wsrc[q * 256 + tid];
  __syncthreads();              // also covers xs/hs init
#pragma unroll
  for (int q = 0; q < 8; ++q)
    ((float4*)&wS[0][0][0])[q * 256 + tid] = stg[q];
  __syncthreads();

  int cur = 0;
  for (int t = 0; t < 10; ++t) {
    float4 acc[8];
#pragma unroll
    for (int r = 0; r < 8; ++r) acc[r] = b1v;

    // x part (K=13)
#pragma unroll
    for (int d = 0; d < 13; ++d) {
      float4 wv = wihv[d];
#pragma unroll
      for (int r = 0; r < 8; ++r) {
        float xv = xs[row0 + r][t * 13 + d];
        acc[r].x = fmaf(xv, wv.x, acc[r].x);
        acc[r].y = fmaf(xv, wv.y, acc[r].y);
        acc[r].z = fmaf(xv, wv.z, acc[r].z);
        acc[r].w = fmaf(xv, wv.w, acc[r].w);
      }
    }

    // h part: 8 chunks of K=16, double-buffered
    for (int ci = 0; ci < 8; ++ci) {
      const int nxtc = (ci + 1) & 7;
#pragma unroll
      for (int q = 0; q < 8; ++q)
        stg[q] = wsrc[nxtc * 2048 + q * 256 + tid];
#pragma unroll
      for (int kk4 = 0; kk4 < 4; ++kk4) {
        float4 w0 = *(const float4*)&wS[cur][kk4 * 4 + 0][4 * u];
        float4 w1 = *(const float4*)&wS[cur][kk4 * 4 + 1][4 * u];
        float4 w2 = *(const float4*)&wS[cur][kk4 * 4 + 2][4 * u];
        float4 w3 = *(const float4*)&wS[cur][kk4 * 4 + 3][4 * u];
#pragma unroll
        for (int r = 0; r < 8; ++r) {
          float4 hv = *(const float4*)&hs[row0 + r][ci * 16 + kk4 * 4];
          acc[r].x = fmaf(hv.x, w0.x, acc[r].x);
          acc[r].y = fmaf(hv.x, w0.y, acc[r].y);
          acc[r].z = fmaf(hv.x, w0.z, acc[r].z);
          acc[r].w = fmaf(hv.x, w0.w, acc[r].w);
          acc[r].x = fmaf(hv.y, w1.x, acc[r].x);
          acc[r].y = fmaf(hv.y, w1.y, acc[r].y);
          acc[r].z = fmaf(hv.y, w1.z, acc[r].z);
          acc[r].w = fmaf(hv.y, w1.w, acc[r].w);
          acc[r].x = fmaf(hv.z, w2.x, acc[r].x);
          acc[r].y = fmaf(hv.z, w2.y, acc[r].y);
          acc[r].z = fmaf(hv.z, w2.z, acc[r].z);
          acc[r].w = fmaf(hv.z, w2.w, acc[r].w);
          acc[r].x = fmaf(hv.w, w3.x, acc[r].x);
          acc[r].y = fmaf(hv.w, w3.y, acc[r].y);
          acc[r].z = fmaf(hv.w, w3.z, acc[r].z);
          acc[r].w = fmaf(hv.w, w3.w, acc[r].w);
        }
      }
      __syncthreads();   // all waves done reading wS[cur^1]'s old chunk
#pragma unroll
      for (int q = 0; q < 8; ++q)
        ((float4*)&wS[cur ^ 1][0][0])[q * 256 + tid] = stg[q];
      __syncthreads();   // new chunk visible
      cur ^= 1;
    }

    // gates + h/c update (thread owns 8 rows x unit u)
#pragma unroll
    for (int r = 0; r < 8; ++r) {
      float ig = sigf(acc[r].x);
      float fg = sigf(acc[r].y);
      float gg = tanhfast(acc[r].z);
      float og = sigf(acc[r].w);
      float c = fmaf(fg, creg[r], ig * gg);
      creg[r] = c;
      hs[row0 + r][u] = og * tanhfast(c);
    }
    __syncthreads();
  }

  // rr = relu(h_final @ Wc + bc): thread (oc=tid&63, rg8=tid>>6) -> 4 rows
  {
    const int oc = tid & 63, rg8 = tid >> 6;  // [0,4)
    float a0 = bc[oc], a1 = a0, a2 = a0, a3 = a0;
    for (int k = 0; k < 128; ++k) {
      float wcv = Wc[k * 64 + oc];
      a0 = fmaf(hs[rg8 * 4 + 0][k], wcv, a0);
      a1 = fmaf(hs[rg8 * 4 + 1][k], wcv, a1);
      a2 = fmaf(hs[rg8 * 4 + 2][k], wcv, a2);
      a3 = fmaf(hs[rg8 * 4 + 3][k], wcv, a3);
    }
    rr[rg8 * 4 + 0][oc] = fmaxf(a0, 0.0f);
    rr[rg8 * 4 + 1][oc] = fmaxf(a1, 0.0f);
    rr[rg8 * 4 + 2][oc] = fmaxf(a2, 0.0f);
    rr[rg8 * 4 + 3][oc] = fmaxf(a3, 0.0f);
  }
  __syncthreads();
  for (int idx = tid; idx < 512; idx += 256) {
    int j = idx >> 6, oc = idx & 63;
    float lo = 0.5f * (rr[j][oc] + rr[j + 8][oc]);
    lo_raw[(8 * b + j) * 64 + oc] = lo;
    atomicAdd(&sloc[oc], lo);
    atomicAdd(&sloc[64 + oc], lo * lo);
  }
  __syncthreads();
  if (tid < 128) gpartial[tid * 256 + b] = sloc[tid];
}

// ---------------------------------------------------------------------------
// helper: BN1 av/bv from gpartial (redundant per block)
// ---------------------------------------------------------------------------
__device__ __forceinline__ void bn1_scales(
    const float* __restrict__ gpartial, const float* __restrict__ g1,
    const float* __restrict__ be1, float* sS, float* av, float* bv)
{
  const int tid = threadIdx.x;
  if (tid < 128) {
    const float4* gp = (const float4*)(gpartial + tid * 256);
    float s = 0.f;
    for (int i = 0; i < 64; ++i) {
      float4 v = gp[i];
      s += (v.x + v.y) + (v.z + v.w);
    }
    sS[tid] = s;
  }
  __syncthreads();
  if (tid < 64) {
    float m = sS[tid] * (1.0f / 2048.0f);
    float var = sS[64 + tid] * (1.0f / 2048.0f) - m * m;
    float rstd = rsqrtf(var + 1e-5f);
    float gg = g1[tid];
    av[tid] = rstd * gg;
    bv[tid] = be1[tid] - m * rstd * gg;
  }
  __syncthreads();
}

// build out-row feature f for (l,n) on the fly
__device__ __forceinline__ float feat(
    int l, int n, int f, const float* __restrict__ ops,
    const float* __restrict__ extra, const float* __restrict__ card,
    const float* __restrict__ lo_raw, const float* av, const float* bv)
{
  int g = l * 128 + n;
  if (f < 15) return ops[g * 15 + f];
  if (f < 22) return extra[g * 7 + (f - 15)];
  if (f < 24) return card[g * 2 + (f - 22)];
  int j = f - 24;
  return lo_raw[g * 64 + j] * av[j] + bv[j];
}

// ---------------------------------------------------------------------------
// K_mid: blocks 0..63: LSTM2 single step on row l=15 (h0=0, c0=0) -> hidA/cidA.
//        block 64: base_all[t][k] for t<15 (row n=0) + zero tree barrier ctr.
// ---------------------------------------------------------------------------
__global__ __launch_bounds__(256) void k_mid(
    const float* __restrict__ ops, const float* __restrict__ extra,
    const float* __restrict__ card, const float* __restrict__ lo_raw,
    const float* __restrict__ gpartial, const float* __restrict__ g1,
    const float* __restrict__ be1, const float* __restrict__ Wih2,
    const float* __restrict__ b2, const float* __restrict__ Win,
    const float* __restrict__ binb, float* __restrict__ hidA,
    float* __restrict__ cidA, float* __restrict__ base_all,
    unsigned int* __restrict__ treebar)
{
  __shared__ float sS[128], av[64], bv[64];
  const int tid = threadIdx.x, bx = blockIdx.x;
  bn1_scales(gpartial, g1, be1, sS, av, bv);

  if (bx < 64) {
    const int idx = bx * 256 + tid;     // [0,16384)
    const int n = idx >> 7, k = idx & 127;
    float ai = b2[k];
    float ag = b2[256 + k];
    float ao = b2[384 + k];
    for (int f = 0; f < 88; ++f) {
      float xv = feat(15, n, f, ops, extra, card, lo_raw, av, bv);
      ai = fmaf(xv, Wih2[f * 512 + k], ai);
      ag = fmaf(xv, Wih2[f * 512 + 256 + k], ag);
      ao = fmaf(xv, Wih2[f * 512 + 384 + k], ao);
    }
    float c0 = sigf(ai) * tanhfast(ag);
    float h0 = sigf(ao) * tanhfast(c0);
    hidA[idx] = h0;
    cidA[idx] = c0;
  } else {
    if (tid == 255) *treebar = 0u;
    for (int idx = tid; idx < 15 * 128; idx += 256) {
      int t = idx >> 7, k = idx & 127;
      float a = binb[k];
      for (int f = 0; f < 88; ++f)
        a = fmaf(feat(t, 0, f, ops, extra, card, lo_raw, av, bv),
                 Win[f * 128 + k], a);
      base_all[idx] = a;
    }
  }
}

// ---------------------------------------------------------------------------
// K_treeall: all 15 TreeLSTM levels fused, device-scope spin barrier between
// levels; weights staged to LDS ONCE. Block 0 runs the head after the last
// barrier. grid 128 = 16 k-blocks x 8 n-blocks, 256 threads.
// ---------------------------------------------------------------------------
union TreeSh {
  struct {
    float wS[10][8][132];
    float rowS[32][132];
    float pS[128][10];
  } tr;
  struct {
    unsigned char pool[49152];   // t1s bf16[128][128] | t2s bf16[128][64]; t4s f32 aliases t1s
    float red[8][128];
    float av[128];
    float bv[128];
  } hd;
};

__global__ __launch_bounds__(256, 1) void k_treeall(
    const int* __restrict__ mapping, const float* __restrict__ WT,
    const float* __restrict__ base_all, const float* __restrict__ blh,
    const float* __restrict__ brh,
    float* __restrict__ hidA, float* __restrict__ cidA,
    float* __restrict__ hidB, float* __restrict__ cidB,
    unsigned int* __restrict__ treebar,
    const float* __restrict__ g2, const float* __restrict__ be2,
    const float* __restrict__ Wt1, const float* __restrict__ bt1,
    const float* __restrict__ g3, const float* __restrict__ be3,
    const float* __restrict__ Wt2, const float* __restrict__ bt2,
    const float* __restrict__ Wo, const float* __restrict__ bo,
    float* __restrict__ dout)
{
  __shared__ TreeSh sh;
  const int tid = threadIdx.x, bx = blockIdx.x;
  const int k0 = (bx & 15) * 8, n0 = (bx >> 4) * 16;

  // stage gate weights once (reused across all 15 levels)
  for (int idx = tid; idx < 10 * 8 * 128; idx += 256) {
    int h = idx & 127, kp = (idx >> 7) & 7, sg = idx >> 10;
    sh.tr.wS[sg][kp][h] = WT[sg * 16384 + (k0 + kp) * 128 + h];
  }

  float* hc = hidA; float* cc = cidA;
  float* hn = hidB; float* cn = cidB;

  for (int s = 0; s < 15; ++s) {
    const int t = 14 - s;
    for (int idx = tid; idx < 4096; idx += 256) {
      int row = idx >> 7, h = idx & 127;  // row = n'*2 + side
      int np_ = row >> 1, side = row & 1;
      int j = mapping[(t * 128 + n0 + np_) * 2 + side];
      sh.tr.rowS[row][h] = (j > 0) ? hc[(j - 1) * 128 + h] : 0.0f;
    }
    __syncthreads();
    {
      const int pr = tid >> 1, side = tid & 1;
      const int np_ = pr >> 3, kp = pr & 7;
      const int rrow = np_ * 2 + side;
      float acc[5] = {0.f, 0.f, 0.f, 0.f, 0.f};
      for (int h = 0; h < 128; h += 8) {
        float4 r0 = *(const float4*)&sh.tr.rowS[rrow][h];
        float4 r1 = *(const float4*)&sh.tr.rowS[rrow][h + 4];
#pragma unroll
        for (int g = 0; g < 5; ++g) {
          float4 w0 = *(const float4*)&sh.tr.wS[side * 5 + g][kp][h];
          float4 w1 = *(const float4*)&sh.tr.wS[side * 5 + g][kp][h + 4];
          acc[g] = fmaf(r0.x, w0.x, acc[g]);
          acc[g] = fmaf(r0.y, w0.y, acc[g]);
          acc[g] = fmaf(r0.z, w0.z, acc[g]);
          acc[g] = fmaf(r0.w, w0.w, acc[g]);
          acc[g] = fmaf(r1.x, w1.x, acc[g]);
          acc[g] = fmaf(r1.y, w1.y, acc[g]);
          acc[g] = fmaf(r1.z, w1.z, acc[g]);
          acc[g] = fmaf(r1.w, w1.w, acc[g]);
        }
      }
#pragma unroll
      for (int g = 0; g < 5; ++g) sh.tr.pS[pr][side * 5 + g] = acc[g];
    }
    __syncthreads();
    if (tid < 128) {
      const int np_ = tid >> 3, kp = tid & 7;
      const int n = n0 + np_, k = k0 + kp;
      const float base = base_all[t * 128 + k];
      float pre[5];
#pragma unroll
      for (int g = 0; g < 5; ++g)
        pre[g] = sh.tr.pS[tid][g] + sh.tr.pS[tid][5 + g] + base +
                 blh[g * 128 + k] + brh[g * 128 + k];
      int jl = mapping[(t * 128 + n) * 2 + 0];
      int jr = mapping[(t * 128 + n) * 2 + 1];
      float lc = (jl > 0) ? cc[(jl - 1) * 128 + k] : 0.0f;
      float rc = (jr > 0) ? cc[(jr - 1) * 128 + k] : 0.0f;
      float i_ = sigf(pre[0]);
      float lf = sigf(pre[1]);
      float rf = sigf(pre[2]);
      float u_ = tanhfast(pre[3]);
      float o_ = sigf(pre[4]);
      float c = i_ * u_ + lf * lc + rf * rc;
      hn[n * 128 + k] = o_ * tanhfast(c);
      cn[n * 128 + k] = c;
    }
    // device-scope barrier between levels
    __syncthreads();
    const unsigned target = 128u * (unsigned)(s + 1);
    const bool wait = (s < 14) || (bx == 0);
    if (tid == 0) {
      __hip_atomic_fetch_add(treebar, 1u, __ATOMIC_RELEASE,
                             __HIP_MEMORY_SCOPE_AGENT);
      if (wait) {
        while (__hip_atomic_load(treebar, __ATOMIC_ACQUIRE,
                                 __HIP_MEMORY_SCOPE_AGENT) < target)
          __builtin_amdgcn_s_sleep(8);
      }
    }
    __syncthreads();
    if (!wait) return;           // non-0 blocks exit after final arrive
    // swap ping-pong
    float* th = hc; hc = hn; hn = th;
    float* tc = cc; cc = cn; cn = tc;
  }

  if (bx != 0) return;

  // ---------------- head on block 0 (hc = final hid) ----------------
  const float* hid = hc;
  __hip_bfloat16 (*t1s)[128] = (__hip_bfloat16(*)[128])sh.hd.pool;
  __hip_bfloat16 (*t2s)[64] = (__hip_bfloat16(*)[64])(sh.hd.pool + 32768);
  float (*t4s)[64] = (float(*)[64])sh.hd.pool;   // aliases t1s (dead by then)
  float (*red)[128] = sh.hd.red;
  float* av = sh.hd.av;
  float* bv = sh.hd.bv;
  __syncthreads();   // tree arrays dead for block 0; head arrays live

  // BN2 stats (128x128)
  {
    int k = tid & 127, q = tid >> 7;  // q in [0,2)
    float s = 0.f, s2 = 0.f;
    for (int r = q * 64; r < q * 64 + 64; ++r) {
      float v = hid[r * 128 + k];
      s += v; s2 += v * v;
    }
    red[q][k] = s;
    red[2 + q][k] = s2;
  }
  __syncthreads();
  if (tid < 128) {
    float s = red[0][tid] + red[1][tid];
    float s2 = red[2][tid] + red[3][tid];
    float m = s * (1.0f / 128.0f);
    float var = s2 * (1.0f / 128.0f) - m * m;
    float rstd = rsqrtf(var + 1e-5f);
    float gg = g2[tid];
    av[tid] = rstd * gg;
    bv[tid] = be2[tid] - m * rstd * gg;
  }
  __syncthreads();
  for (int idx = tid; idx < 16384; idx += 256) {
    int n = idx >> 7, k = idx & 127;
    t1s[n][k] = __float2bfloat16(hid[idx] * av[k] + bv[k]);
  }
  __syncthreads();
  // t2 = relu(t1 @ Wt1 + bt1)
  for (int idx = tid; idx < 8192; idx += 256) {
    int n = idx >> 6, j = idx & 63;
    float a = bt1[j];
    for (int k = 0; k < 128; ++k)
      a = fmaf(__bfloat162float(t1s[n][k]), Wt1[k * 64 + j], a);
    t2s[n][j] = __float2bfloat16(fmaxf(a, 0.0f));
  }
  __syncthreads();
  // BN3 stats (128x64)
  {
    int j = tid & 63, q = tid >> 6;  // q in [0,4)
    float s = 0.f, s2 = 0.f;
    for (int r = q * 32; r < q * 32 + 32; ++r) {
      float v = __bfloat162float(t2s[r][j]);
      s += v; s2 += v * v;
    }
    red[q][j] = s;
    red[4 + q][j] = s2;
  }
  __syncthreads();
  if (tid < 64) {
    float s = 0.f, s2 = 0.f;
#pragma unroll
    for (int q = 0; q < 4; ++q) { s += red[q][tid]; s2 += red[4 + q][tid]; }
    float m = s * (1.0f / 128.0f);
    float var = s2 * (1.0f / 128.0f) - m * m;
    float rstd = rsqrtf(var + 1e-5f);
    float gg = g3[tid];
    av[tid] = rstd * gg;
    bv[tid] = be3[tid] - m * rstd * gg;
  }
  __syncthreads();
  // t4 = relu(bn3(t2) @ Wt2 + bt2); t4s aliases t1s (t1s dead)
  for (int idx = tid; idx < 8192; idx += 256) {
    int n = idx >> 6, j2 = idx & 63;
    float a = bt2[j2];
    for (int jj = 0; jj < 64; ++jj) {
      float x = __bfloat162float(t2s[n][jj]) * av[jj] + bv[jj];
      a = fmaf(x, Wt2[jj * 64 + j2], a);
    }
    t4s[n][j2] = fmaxf(a, 0.0f);
  }
  __syncthreads();
  if (tid < 128) {
    float a = bo[0];
    for (int j = 0; j < 64; ++j) a = fmaf(t4s[tid][j], Wo[j], a);
    dout[tid] = sigf(a);
  }
}

// ---------------------------------------------------------------------------
extern "C" void kernel_launch(void* const* d_in, const int* in_sizes, int n_in,
                              void* d_out, int out_size, void* d_ws,
                              size_t ws_size, hipStream_t stream)
{
  (void)in_sizes; (void)n_in; (void)out_size; (void)ws_size;
  const float* ops   = (const float*)d_in[0];
  const float* extra = (const float*)d_in[1];
  const float* card  = (const float*)d_in[2];
  const float* cond1 = (const float*)d_in[3];
  const float* cond2 = (const float*)d_in[4];
  const int* mapping = (const int*)d_in[5];
  const float* Wih1 = (const float*)d_in[6];
  const float* Whh1 = (const float*)d_in[7];
  const float* b1   = (const float*)d_in[8];
  const float* Wc   = (const float*)d_in[9];
  const float* bc   = (const float*)d_in[10];
  const float* g1   = (const float*)d_in[11];
  const float* be1  = (const float*)d_in[12];
  const float* Wih2 = (const float*)d_in[13];
  // d_in[14] = Whh2: unused (h0 = 0 in the single-step LSTM2)
  const float* b2   = (const float*)d_in[15];
  const float* Win  = (const float*)d_in[16];
  const float* binb = (const float*)d_in[17];
  const float* Wlh  = (const float*)d_in[18];
  const float* blh  = (const float*)d_in[19];
  const float* Wrh  = (const float*)d_in[20];
  const float* brh  = (const float*)d_in[21];
  const float* g2   = (const float*)d_in[22];
  const float* be2  = (const float*)d_in[23];
  const float* Wt1  = (const float*)d_in[24];
  const float* bt1  = (const float*)d_in[25];
  const float* g3   = (const float*)d_in[26];
  const float* be3  = (const float*)d_in[27];
  const float* Wt2  = (const float*)d_in[28];
  const float* bt2  = (const float*)d_in[29];
  const float* Wo   = (const float*)d_in[30];
  const float* bo   = (const float*)d_in[31];

  char* ws = (char*)d_ws;
  float* WhhP     = (float*)(ws + 0);        // 128x512 f32 = 256KB
  float* WihP     = (float*)(ws + 262144);   // 13x512 f32
  float* b1P      = (float*)(ws + 288768);   // 512 f32
  float* gpartial = (float*)(ws + 290816);   // 128x256 f32 = 128KB
  float* lo_raw   = (float*)(ws + 421888);   // 2048x64 f32
  float* base_all = (float*)(ws + 946176);   // 15x128 f32
  float* WT       = (float*)(ws + 953856);   // 10x128x128 f32
  float* hidA     = (float*)(ws + 1609216);  // 128x128 f32 x4
  float* hidB     = hidA + 16384;
  float* cidA     = hidB + 16384;
  float* cidB     = cidA + 16384;
  unsigned int* treebar = (unsigned int*)(ws + 1871360);

  k_pre<<<dim3(43), dim3(256), 0, stream>>>(
      Whh1, Wih1, b1, Wlh, Wrh, WhhP, WihP, b1P, WT);
  k_lstm1<<<dim3(256), dim3(256), 0, stream>>>(
      cond1, cond2, WihP, WhhP, b1P, Wc, bc, lo_raw, gpartial);
  k_mid<<<dim3(65), dim3(256), 0, stream>>>(
      ops, extra, card, lo_raw, gpartial, g1, be1, Wih2, b2, Win, binb,
      hidA, cidA, base_all, treebar);
  k_treeall<<<dim3(128), dim3(256), 0, stream>>>(
      mapping, WT, base_all, blh, brh, hidA, cidA, hidB, cidB, treebar,
      g2, be2, Wt1, bt1, g3, be3, Wt2, bt2, Wo, bo, (float*)d_out);
}

// Round 6
// 770.346 us; speedup vs baseline: 1.2349x; 1.2349x over previous
//
#include <hip/hip_runtime.h>
#include <hip/hip_bf16.h>

__device__ __forceinline__ float sigf(float x) {
  return __fdividef(1.0f, 1.0f + __expf(-x));
}
__device__ __forceinline__ float tanhfast(float x) {
  float e = __expf(2.0f * x);
  return 1.0f - __fdividef(2.0f, e + 1.0f);
}
// MALL-coherent accessors (sc1, bypass non-coherent per-XCD L2). Relaxed: no
// cache invalidate/writeback side effects (round-4 lesson).
__device__ __forceinline__ float aload(const float* p) {
  return __hip_atomic_load(p, __ATOMIC_RELAXED, __HIP_MEMORY_SCOPE_AGENT);
}
__device__ __forceinline__ void astore(float* p, float v) {
  __hip_atomic_store(p, v, __ATOMIC_RELAXED, __HIP_MEMORY_SCOPE_AGENT);
}

// ---------------------------------------------------------------------------
// K_pre: permuted weights + transposed tree weights.
//  WhhP[k][u*4+g] = Whh1[k][g*128+u]; WihP[d][u*4+g]; b1P[u*4+g];
//  WT[m][k][h] = (m<5?Wlh:Wrh)[m%5][h][k]
// ---------------------------------------------------------------------------
__global__ __launch_bounds__(256) void k_pre(
    const float* __restrict__ Whh1, const float* __restrict__ Wih1,
    const float* __restrict__ b1, const float* __restrict__ Wlh,
    const float* __restrict__ Wrh,
    float* __restrict__ WhhP, float* __restrict__ WihP,
    float* __restrict__ b1P, float* __restrict__ WT)
{
  const int bx = blockIdx.x, tid = threadIdx.x;
  if (bx < 32) {
    for (int i = 0; i < 8; ++i) {
      int dst = bx * 2048 + i * 256 + tid;
      int g = dst & 3, u = (dst >> 2) & 127, k = dst >> 9;
      WhhP[dst] = Whh1[k * 512 + g * 128 + u];
    }
  } else if (bx == 32) {
    for (int idx = tid; idx < 13 * 512; idx += 256) {
      int g = idx & 3, u = (idx >> 2) & 127, d = idx >> 9;
      WihP[idx] = Wih1[d * 512 + g * 128 + u];
    }
    for (int idx = tid; idx < 512; idx += 256)
      b1P[idx] = b1[(idx & 3) * 128 + (idx >> 2)];
  } else {
    __shared__ float tile[32][33];
    const int m = bx - 33;                 // 0..9 = side*5+g
    const int side = m / 5, g = m - side * 5;
    const float* src = (side ? Wrh : Wlh) + g * 16384;
    float* dst = WT + m * 16384;
    const int i = tid >> 5, jj = tid & 31;
    for (int tt = 0; tt < 16; ++tt) {
      const int ti = tt >> 2, tj = tt & 3;
#pragma unroll
      for (int q = 0; q < 4; ++q)
        tile[i + q * 8][jj] = src[(ti * 32 + i + q * 8) * 128 + tj * 32 + jj];
      __syncthreads();
#pragma unroll
      for (int q = 0; q < 4; ++q)
        dst[(tj * 32 + i + q * 8) * 128 + ti * 32 + jj] = tile[jj][i + q * 8];
      __syncthreads();
    }
  }
}

// ---------------------------------------------------------------------------
// K1: LSTM1, 256 blocks x 512 threads, 16 seqs/block (8 cond1 + 8 cond2).
// Thread (u = tid&127, rg = tid>>7): holds Whh slice k in [32rg,32rg+32) for
// unit u's 4 gates in 128 VGPRs (zero LDS weight traffic). h-reads are
// wave-uniform LDS broadcasts. Rows processed in 2 halves of 8 so the
// cross-slice partial buffer pS is 64KB. Thread (u,q=rg) owns cell state for
// rows {2q,2q+1,8+2q,9+2q}. 4 barriers per timestep.
// Epilogue: relu(h@Wc+bc) pairs -> lo, per-block BN1 partials -> gpartial.
// ---------------------------------------------------------------------------
__global__ __launch_bounds__(512, 1) void k_lstm1(
    const float* __restrict__ cond1, const float* __restrict__ cond2,
    const float* __restrict__ WihP, const float* __restrict__ WhhP,
    const float* __restrict__ b1P, const float* __restrict__ Wc,
    const float* __restrict__ bc,
    float* __restrict__ lo_raw, float* __restrict__ gpartial)
{
  __shared__ float4 pS[4][8][128];    // 64KB partial gate sums [rg][row8][u]
  __shared__ float4 hs4[16][32];      // 8KB h state, h[row][4q+c]
  __shared__ float  xs[16][132];      // inputs, 10 steps x 13
  __shared__ float4 WihS[13][128];    // 26.6KB Wih permuted
  __shared__ float  rr[16][64];
  __shared__ float  sloc[128];

  const int tid = threadIdx.x, b = blockIdx.x;
  const int u = tid & 127, rg = tid >> 7;   // rg = k-slice owner = row-pair q

  for (int idx = tid; idx < 16 * 130; idx += 512) {
    int r = idx / 130, d = idx - r * 130;
    xs[r][d] = (r < 8) ? cond1[(8 * b + r) * 130 + d]
                       : cond2[(8 * b + (r - 8)) * 130 + d];
  }
  for (int idx = tid; idx < 13 * 128; idx += 512)
    WihS[idx >> 7][idx & 127] =
        *(const float4*)&WihP[(idx >> 7) * 512 + 4 * (idx & 127)];
  ((float4*)hs4)[tid] = make_float4(0.f, 0.f, 0.f, 0.f);  // 512 entries
  if (tid < 128) sloc[tid] = 0.f;

  float4 w[32];
#pragma unroll
  for (int kk = 0; kk < 32; ++kk)
    w[kk] = *(const float4*)&WhhP[(32 * rg + kk) * 512 + 4 * u];
  const float4 b1v = *(const float4*)&b1P[4 * u];
  float creg[4] = {0.f, 0.f, 0.f, 0.f};   // rows 2rg, 2rg+1, 8+2rg, 9+2rg
  __syncthreads();

  for (int t = 0; t < 10; ++t) {
#pragma unroll
    for (int hf = 0; hf < 2; ++hf) {
      const int base = 8 * hf;
      // phase A: partials over this thread's k-slice for rows base..base+7
#pragma unroll
      for (int row = 0; row < 8; ++row) {
        float4 a = make_float4(0.f, 0.f, 0.f, 0.f);
#pragma unroll
        for (int q = 0; q < 8; ++q) {
          const float4 hv = hs4[base + row][8 * rg + q];  // broadcast
          const float4 w0 = w[4 * q + 0], w1 = w[4 * q + 1];
          const float4 w2 = w[4 * q + 2], w3 = w[4 * q + 3];
          a.x = fmaf(hv.x, w0.x, a.x); a.y = fmaf(hv.x, w0.y, a.y);
          a.z = fmaf(hv.x, w0.z, a.z); a.w = fmaf(hv.x, w0.w, a.w);
          a.x = fmaf(hv.y, w1.x, a.x); a.y = fmaf(hv.y, w1.y, a.y);
          a.z = fmaf(hv.y, w1.z, a.z); a.w = fmaf(hv.y, w1.w, a.w);
          a.x = fmaf(hv.z, w2.x, a.x); a.y = fmaf(hv.z, w2.y, a.y);
          a.z = fmaf(hv.z, w2.z, a.z); a.w = fmaf(hv.z, w2.w, a.w);
          a.x = fmaf(hv.w, w3.x, a.x); a.y = fmaf(hv.w, w3.y, a.y);
          a.z = fmaf(hv.w, w3.z, a.z); a.w = fmaf(hv.w, w3.w, a.w);
        }
        pS[rg][row][u] = a;
      }
      __syncthreads();   // pS visible; all hs reads of this half done
      // phase B: thread (u, rg) finishes rows base+2rg, base+2rg+1
      {
        float4 gs[2];
#pragma unroll
        for (int i = 0; i < 2; ++i) {
          const int rh = 2 * rg + i;
          float4 s0 = pS[0][rh][u], s1 = pS[1][rh][u];
          float4 s2 = pS[2][rh][u], s3 = pS[3][rh][u];
          gs[i].x = ((s0.x + s1.x) + (s2.x + s3.x)) + b1v.x;
          gs[i].y = ((s0.y + s1.y) + (s2.y + s3.y)) + b1v.y;
          gs[i].z = ((s0.z + s1.z) + (s2.z + s3.z)) + b1v.z;
          gs[i].w = ((s0.w + s1.w) + (s2.w + s3.w)) + b1v.w;
        }
#pragma unroll
        for (int d = 0; d < 13; ++d) {
          const float4 wv = WihS[d][u];
#pragma unroll
          for (int i = 0; i < 2; ++i) {
            const float xv = xs[base + 2 * rg + i][t * 13 + d];
            gs[i].x = fmaf(xv, wv.x, gs[i].x);
            gs[i].y = fmaf(xv, wv.y, gs[i].y);
            gs[i].z = fmaf(xv, wv.z, gs[i].z);
            gs[i].w = fmaf(xv, wv.w, gs[i].w);
          }
        }
#pragma unroll
        for (int i = 0; i < 2; ++i) {
          const int row = base + 2 * rg + i;
          const int ci = 2 * hf + i;
          float ig = sigf(gs[i].x);
          float fg = sigf(gs[i].y);
          float gg = tanhfast(gs[i].z);
          float og = sigf(gs[i].w);
          float c = fmaf(fg, creg[ci], ig * gg);
          creg[ci] = c;
          ((float*)&hs4[row][0])[u] = og * tanhfast(c);
        }
      }
      __syncthreads();   // hs writes visible before next half/timestep
    }
  }

  // epilogue: rr = relu(h_final @ Wc + bc); 2 rows per thread
  {
    const int oc = tid & 63, r8 = tid >> 6;  // r8 in [0,8)
    const float* h0 = (const float*)&hs4[2 * r8][0];
    const float* h1 = (const float*)&hs4[2 * r8 + 1][0];
    float a0 = bc[oc], a1 = a0;
    for (int k = 0; k < 128; ++k) {
      float wcv = Wc[k * 64 + oc];
      a0 = fmaf(h0[k], wcv, a0);
      a1 = fmaf(h1[k], wcv, a1);
    }
    rr[2 * r8][oc] = fmaxf(a0, 0.f);
    rr[2 * r8 + 1][oc] = fmaxf(a1, 0.f);
  }
  __syncthreads();
  {
    const int j = tid >> 6, oc = tid & 63;   // 512 = 8 rows x 64 cols
    float lo = 0.5f * (rr[j][oc] + rr[j + 8][oc]);
    lo_raw[(8 * b + j) * 64 + oc] = lo;
    atomicAdd(&sloc[oc], lo);
    atomicAdd(&sloc[64 + oc], lo * lo);
  }
  __syncthreads();
  if (tid < 128) gpartial[tid * 256 + b] = sloc[tid];
}

// ---------------------------------------------------------------------------
// helper: BN1 av/bv from gpartial (redundant per block)
// ---------------------------------------------------------------------------
__device__ __forceinline__ void bn1_scales(
    const float* __restrict__ gpartial, const float* __restrict__ g1,
    const float* __restrict__ be1, float* sS, float* av, float* bv)
{
  const int tid = threadIdx.x;
  if (tid < 128) {
    const float4* gp = (const float4*)(gpartial + tid * 256);
    float s = 0.f;
    for (int i = 0; i < 64; ++i) {
      float4 v = gp[i];
      s += (v.x + v.y) + (v.z + v.w);
    }
    sS[tid] = s;
  }
  __syncthreads();
  if (tid < 64) {
    float m = sS[tid] * (1.0f / 2048.0f);
    float var = sS[64 + tid] * (1.0f / 2048.0f) - m * m;
    float rstd = rsqrtf(var + 1e-5f);
    float gg = g1[tid];
    av[tid] = rstd * gg;
    bv[tid] = be1[tid] - m * rstd * gg;
  }
  __syncthreads();
}

__device__ __forceinline__ float feat(
    int l, int n, int f, const float* __restrict__ ops,
    const float* __restrict__ extra, const float* __restrict__ card,
    const float* __restrict__ lo_raw, const float* av, const float* bv)
{
  int g = l * 128 + n;
  if (f < 15) return ops[g * 15 + f];
  if (f < 22) return extra[g * 7 + (f - 15)];
  if (f < 24) return card[g * 2 + (f - 22)];
  int j = f - 24;
  return lo_raw[g * 64 + j] * av[j] + bv[j];
}

// ---------------------------------------------------------------------------
// K_mid: blocks 0..63: LSTM2 single step (h0=c0=0) -> hidA/cidA.
//        block 64: base_all + zero tree barrier counter.
// ---------------------------------------------------------------------------
__global__ __launch_bounds__(256) void k_mid(
    const float* __restrict__ ops, const float* __restrict__ extra,
    const float* __restrict__ card, const float* __restrict__ lo_raw,
    const float* __restrict__ gpartial, const float* __restrict__ g1,
    const float* __restrict__ be1, const float* __restrict__ Wih2,
    const float* __restrict__ b2, const float* __restrict__ Win,
    const float* __restrict__ binb, float* __restrict__ hidA,
    float* __restrict__ cidA, float* __restrict__ base_all,
    unsigned int* __restrict__ treebar)
{
  __shared__ float sS[128], av[64], bv[64];
  const int tid = threadIdx.x, bx = blockIdx.x;
  bn1_scales(gpartial, g1, be1, sS, av, bv);

  if (bx < 64) {
    const int idx = bx * 256 + tid;
    const int n = idx >> 7, k = idx & 127;
    float ai = b2[k];
    float ag = b2[256 + k];
    float ao = b2[384 + k];
    for (int f = 0; f < 88; ++f) {
      float xv = feat(15, n, f, ops, extra, card, lo_raw, av, bv);
      ai = fmaf(xv, Wih2[f * 512 + k], ai);
      ag = fmaf(xv, Wih2[f * 512 + 256 + k], ag);
      ao = fmaf(xv, Wih2[f * 512 + 384 + k], ao);
    }
    float c0 = sigf(ai) * tanhfast(ag);
    float h0 = sigf(ao) * tanhfast(c0);
    hidA[idx] = h0;
    cidA[idx] = c0;
  } else {
    if (tid == 255) *treebar = 0u;
    for (int idx = tid; idx < 15 * 128; idx += 256) {
      int t = idx >> 7, k = idx & 127;
      float a = binb[k];
      for (int f = 0; f < 88; ++f)
        a = fmaf(feat(t, 0, f, ops, extra, card, lo_raw, av, bv),
                 Win[f * 128 + k], a);
      base_all[idx] = a;
    }
  }
}

// ---------------------------------------------------------------------------
// K_treeall: all 15 levels fused. Cross-block state via relaxed agent-scope
// (sc1 / MALL-coherent) atomics -> NO acquire invalidates, NO L2 thrash.
// Barrier: __syncthreads (drains stores) -> release add -> RELAXED polls.
// Block 0 runs the head after the final level. grid 128 x 256.
// ---------------------------------------------------------------------------
union TreeSh {
  struct {
    float wS[10][8][132];
    float rowS[32][132];
    float pS[10][132];     // transposed partials: [side*5+g][pr]
  } tr;
  struct {
    unsigned char pool[49152];  // t1s bf16[128][128] | t2s bf16[128][64]
    float red[8][128];
    float av[128];
    float bv[128];
  } hd;
};

__global__ __launch_bounds__(256, 1) void k_treeall(
    const int* __restrict__ mapping, const float* __restrict__ WT,
    const float* __restrict__ base_all, const float* __restrict__ blh,
    const float* __restrict__ brh,
    float* __restrict__ hidA, float* __restrict__ cidA,
    float* __restrict__ hidB, float* __restrict__ cidB,
    unsigned int* __restrict__ treebar,
    const float* __restrict__ g2, const float* __restrict__ be2,
    const float* __restrict__ Wt1, const float* __restrict__ bt1,
    const float* __restrict__ g3, const float* __restrict__ be3,
    const float* __restrict__ Wt2, const float* __restrict__ bt2,
    const float* __restrict__ Wo, const float* __restrict__ bo,
    float* __restrict__ dout)
{
  __shared__ TreeSh sh;
  const int tid = threadIdx.x, bx = blockIdx.x;
  const int k0 = (bx & 15) * 8, n0 = (bx >> 4) * 16;

  for (int idx = tid; idx < 10 * 8 * 128; idx += 256) {
    int h = idx & 127, kp = (idx >> 7) & 7, sg = idx >> 10;
    sh.tr.wS[sg][kp][h] = WT[sg * 16384 + (k0 + kp) * 128 + h];
  }

  float* hc = hidA; float* cc = cidA;
  float* hn = hidB; float* cn = cidB;

  for (int s = 0; s < 15; ++s) {
    const int t = 14 - s;
    for (int idx = tid; idx < 4096; idx += 256) {
      int row = idx >> 7, h = idx & 127;
      int np_ = row >> 1, side = row & 1;
      int j = mapping[(t * 128 + n0 + np_) * 2 + side];
      sh.tr.rowS[row][h] = (j > 0) ? aload(&hc[(j - 1) * 128 + h]) : 0.0f;
    }
    __syncthreads();
    {
      const int pr = tid >> 1, side = tid & 1;
      const int np_ = pr >> 3, kp = pr & 7;
      const int rrow = np_ * 2 + side;
      float acc[5] = {0.f, 0.f, 0.f, 0.f, 0.f};
      for (int h = 0; h < 128; h += 8) {
        float4 r0 = *(const float4*)&sh.tr.rowS[rrow][h];
        float4 r1 = *(const float4*)&sh.tr.rowS[rrow][h + 4];
#pragma unroll
        for (int g = 0; g < 5; ++g) {
          float4 w0 = *(const float4*)&sh.tr.wS[side * 5 + g][kp][h];
          float4 w1 = *(const float4*)&sh.tr.wS[side * 5 + g][kp][h + 4];
          acc[g] = fmaf(r0.x, w0.x, acc[g]);
          acc[g] = fmaf(r0.y, w0.y, acc[g]);
          acc[g] = fmaf(r0.z, w0.z, acc[g]);
          acc[g] = fmaf(r0.w, w0.w, acc[g]);
          acc[g] = fmaf(r1.x, w1.x, acc[g]);
          acc[g] = fmaf(r1.y, w1.y, acc[g]);
          acc[g] = fmaf(r1.z, w1.z, acc[g]);
          acc[g] = fmaf(r1.w, w1.w, acc[g]);
        }
      }
#pragma unroll
      for (int g = 0; g < 5; ++g) sh.tr.pS[side * 5 + g][pr] = acc[g];
    }
    __syncthreads();
    if (tid < 128) {
      const int np_ = tid >> 3, kp = tid & 7;
      const int n = n0 + np_, k = k0 + kp;
      const float base = base_all[t * 128 + k];
      float pre[5];
#pragma unroll
      for (int g = 0; g < 5; ++g)
        pre[g] = sh.tr.pS[g][tid] + sh.tr.pS[5 + g][tid] + base +
                 blh[g * 128 + k] + brh[g * 128 + k];
      int jl = mapping[(t * 128 + n) * 2 + 0];
      int jr = mapping[(t * 128 + n) * 2 + 1];
      float lc = (jl > 0) ? aload(&cc[(jl - 1) * 128 + k]) : 0.0f;
      float rc = (jr > 0) ? aload(&cc[(jr - 1) * 128 + k]) : 0.0f;
      float i_ = sigf(pre[0]);
      float lf = sigf(pre[1]);
      float rf = sigf(pre[2]);
      float u_ = tanhfast(pre[3]);
      float o_ = sigf(pre[4]);
      float c = i_ * u_ + lf * lc + rf * rc;
      astore(&hn[n * 128 + k], o_ * tanhfast(c));
      astore(&cn[n * 128 + k], c);
    }
    // barrier: syncthreads drains every wave's stores (vmcnt(0) before
    // s_barrier), then release add; polls are RELAXED (no L2 invalidate).
    __syncthreads();
    const unsigned target = 128u * (unsigned)(s + 1);
    const bool wait = (s < 14) || (bx == 0);
    if (tid == 0) {
      __hip_atomic_fetch_add(treebar, 1u, __ATOMIC_RELEASE,
                             __HIP_MEMORY_SCOPE_AGENT);
      if (wait) {
        while (__hip_atomic_load(treebar, __ATOMIC_RELAXED,
                                 __HIP_MEMORY_SCOPE_AGENT) < target)
          __builtin_amdgcn_s_sleep(1);
      }
    }
    __syncthreads();
    if (!wait) return;
    float* th = hc; hc = hn; hn = th;
    float* tc = cc; cc = cn; cn = tc;
  }

  if (bx != 0) return;

  // ---------------- head on block 0 (hc = final hid) ----------------
  const float* hid = hc;
  __hip_bfloat16 (*t1s)[128] = (__hip_bfloat16(*)[128])sh.hd.pool;
  __hip_bfloat16 (*t2s)[64] = (__hip_bfloat16(*)[64])(sh.hd.pool + 32768);
  float (*t4s)[64] = (float(*)[64])sh.hd.pool;   // aliases t1s (dead by then)
  float (*red)[128] = sh.hd.red;
  float* av = sh.hd.av;
  float* bv = sh.hd.bv;
  __syncthreads();

  {
    int k = tid & 127, q = tid >> 7;  // q in [0,2)
    float s = 0.f, s2 = 0.f;
    for (int r = q * 64; r < q * 64 + 64; ++r) {
      float v = aload(&hid[r * 128 + k]);
      s += v; s2 += v * v;
    }
    red[q][k] = s;
    red[2 + q][k] = s2;
  }
  __syncthreads();
  if (tid < 128) {
    float s = red[0][tid] + red[1][tid];
    float s2 = red[2][tid] + red[3][tid];
    float m = s * (1.0f / 128.0f);
    float var = s2 * (1.0f / 128.0f) - m * m;
    float rstd = rsqrtf(var + 1e-5f);
    float gg = g2[tid];
    av[tid] = rstd * gg;
    bv[tid] = be2[tid] - m * rstd * gg;
  }
  __syncthreads();
  for (int idx = tid; idx < 16384; idx += 256) {
    int n = idx >> 7, k = idx & 127;
    t1s[n][k] = __float2bfloat16(aload(&hid[idx]) * av[k] + bv[k]);
  }
  __syncthreads();
  for (int idx = tid; idx < 8192; idx += 256) {
    int n = idx >> 6, j = idx & 63;
    float a = bt1[j];
    for (int k = 0; k < 128; ++k)
      a = fmaf(__bfloat162float(t1s[n][k]), Wt1[k * 64 + j], a);
    t2s[n][j] = __float2bfloat16(fmaxf(a, 0.0f));
  }
  __syncthreads();
  {
    int j = tid & 63, q = tid >> 6;  // q in [0,4)
    float s = 0.f, s2 = 0.f;
    for (int r = q * 32; r < q * 32 + 32; ++r) {
      float v = __bfloat162float(t2s[r][j]);
      s += v; s2 += v * v;
    }
    red[q][j] = s;
    red[4 + q][j] = s2;
  }
  __syncthreads();
  if (tid < 64) {
    float s = 0.f, s2 = 0.f;
#pragma unroll
    for (int q = 0; q < 4; ++q) { s += red[q][tid]; s2 += red[4 + q][tid]; }
    float m = s * (1.0f / 128.0f);
    float var = s2 * (1.0f / 128.0f) - m * m;
    float rstd = rsqrtf(var + 1e-5f);
    float gg = g3[tid];
    av[tid] = rstd * gg;
    bv[tid] = be3[tid] - m * rstd * gg;
  }
  __syncthreads();
  for (int idx = tid; idx < 8192; idx += 256) {
    int n = idx >> 6, j2 = idx & 63;
    float a = bt2[j2];
    for (int jj = 0; jj < 64; ++jj) {
      float x = __bfloat162float(t2s[n][jj]) * av[jj] + bv[jj];
      a = fmaf(x, Wt2[jj * 64 + j2], a);
    }
    t4s[n][j2] = fmaxf(a, 0.0f);
  }
  __syncthreads();
  if (tid < 128) {
    float a = bo[0];
    for (int j = 0; j < 64; ++j) a = fmaf(t4s[tid][j], Wo[j], a);
    dout[tid] = sigf(a);
  }
}

// ---------------------------------------------------------------------------
extern "C" void kernel_launch(void* const* d_in, const int* in_sizes, int n_in,
                              void* d_out, int out_size, void* d_ws,
                              size_t ws_size, hipStream_t stream)
{
  (void)in_sizes; (void)n_in; (void)out_size; (void)ws_size;
  const float* ops   = (const float*)d_in[0];
  const float* extra = (const float*)d_in[1];
  const float* card  = (const float*)d_in[2];
  const float* cond1 = (const float*)d_in[3];
  const float* cond2 = (const float*)d_in[4];
  const int* mapping = (const int*)d_in[5];
  const float* Wih1 = (const float*)d_in[6];
  const float* Whh1 = (const float*)d_in[7];
  const float* b1   = (const float*)d_in[8];
  const float* Wc   = (const float*)d_in[9];
  const float* bc   = (const float*)d_in[10];
  const float* g1   = (const float*)d_in[11];
  const float* be1  = (const float*)d_in[12];
  const float* Wih2 = (const float*)d_in[13];
  // d_in[14] = Whh2: unused (h0 = 0 in the single-step LSTM2)
  const float* b2   = (const float*)d_in[15];
  const float* Win  = (const float*)d_in[16];
  const float* binb = (const float*)d_in[17];
  const float* Wlh  = (const float*)d_in[18];
  const float* blh  = (const float*)d_in[19];
  const float* Wrh  = (const float*)d_in[20];
  const float* brh  = (const float*)d_in[21];
  const float* g2   = (const float*)d_in[22];
  const float* be2  = (const float*)d_in[23];
  const float* Wt1  = (const float*)d_in[24];
  const float* bt1  = (const float*)d_in[25];
  const float* g3   = (const float*)d_in[26];
  const float* be3  = (const float*)d_in[27];
  const float* Wt2  = (const float*)d_in[28];
  const float* bt2  = (const float*)d_in[29];
  const float* Wo   = (const float*)d_in[30];
  const float* bo   = (const float*)d_in[31];

  char* ws = (char*)d_ws;
  float* WhhP     = (float*)(ws + 0);        // 128x512 f32 = 256KB
  float* WihP     = (float*)(ws + 262144);   // 13x512 f32
  float* b1P      = (float*)(ws + 288768);   // 512 f32
  float* gpartial = (float*)(ws + 290816);   // 128x256 f32 = 128KB
  float* lo_raw   = (float*)(ws + 421888);   // 2048x64 f32
  float* base_all = (float*)(ws + 946176);   // 15x128 f32
  float* WT       = (float*)(ws + 953856);   // 10x128x128 f32
  float* hidA     = (float*)(ws + 1609216);  // 128x128 f32 x4
  float* hidB     = hidA + 16384;
  float* cidA     = hidB + 16384;
  float* cidB     = cidA + 16384;
  unsigned int* treebar = (unsigned int*)(ws + 1871360);

  k_pre<<<dim3(43), dim3(256), 0, stream>>>(
      Whh1, Wih1, b1, Wlh, Wrh, WhhP, WihP, b1P, WT);
  k_lstm1<<<dim3(256), dim3(512), 0, stream>>>(
      cond1, cond2, WihP, WhhP, b1P, Wc, bc, lo_raw, gpartial);
  k_mid<<<dim3(65), dim3(256), 0, stream>>>(
      ops, extra, card, lo_raw, gpartial, g1, be1, Wih2, b2, Win, binb,
      hidA, cidA, base_all, treebar);
  k_treeall<<<dim3(128), dim3(256), 0, stream>>>(
      mapping, WT, base_all, blh, brh, hidA, cidA, hidB, cidB, treebar,
      g2, be2, Wt1, bt1, g3, be3, Wt2, bt2, Wo, bo, (float*)d_out);
}

// Round 7
// 563.408 us; speedup vs baseline: 1.6885x; 1.3673x over previous
//
#include <hip/hip_runtime.h>
#include <hip/hip_bf16.h>

__device__ __forceinline__ float sigf(float x) {
  return __fdividef(1.0f, 1.0f + __expf(-x));
}
__device__ __forceinline__ float tanhfast(float x) {
  float e = __expf(2.0f * x);
  return 1.0f - __fdividef(2.0f, e + 1.0f);
}

// ---------------------------------------------------------------------------
// K_pre: permuted weights + transposed tree weights.
//  WhhP[k][u*4+g] = Whh1[k][g*128+u]; WihP[d][u*4+g]; b1P[u*4+g];
//  WT[m][k][h] = (m<5?Wlh:Wrh)[m%5][h][k]
// ---------------------------------------------------------------------------
__global__ __launch_bounds__(256) void k_pre(
    const float* __restrict__ Whh1, const float* __restrict__ Wih1,
    const float* __restrict__ b1, const float* __restrict__ Wlh,
    const float* __restrict__ Wrh,
    float* __restrict__ WhhP, float* __restrict__ WihP,
    float* __restrict__ b1P, float* __restrict__ WT)
{
  const int bx = blockIdx.x, tid = threadIdx.x;
  if (bx < 32) {
    for (int i = 0; i < 8; ++i) {
      int dst = bx * 2048 + i * 256 + tid;
      int g = dst & 3, u = (dst >> 2) & 127, k = dst >> 9;
      WhhP[dst] = Whh1[k * 512 + g * 128 + u];
    }
  } else if (bx == 32) {
    for (int idx = tid; idx < 13 * 512; idx += 256) {
      int g = idx & 3, u = (idx >> 2) & 127, d = idx >> 9;
      WihP[idx] = Wih1[d * 512 + g * 128 + u];
    }
    for (int idx = tid; idx < 512; idx += 256)
      b1P[idx] = b1[(idx & 3) * 128 + (idx >> 2)];
  } else {
    __shared__ float tile[32][33];
    const int m = bx - 33;                 // 0..9 = side*5+g
    const int side = m / 5, g = m - side * 5;
    const float* src = (side ? Wrh : Wlh) + g * 16384;
    float* dst = WT + m * 16384;
    const int i = tid >> 5, jj = tid & 31;
    for (int tt = 0; tt < 16; ++tt) {
      const int ti = tt >> 2, tj = tt & 3;
#pragma unroll
      for (int q = 0; q < 4; ++q)
        tile[i + q * 8][jj] = src[(ti * 32 + i + q * 8) * 128 + tj * 32 + jj];
      __syncthreads();
#pragma unroll
      for (int q = 0; q < 4; ++q)
        dst[(tj * 32 + i + q * 8) * 128 + ti * 32 + jj] = tile[jj][i + q * 8];
      __syncthreads();
    }
  }
}

// ---------------------------------------------------------------------------
// K1: LSTM1, 256 blocks x 512 threads, 16 seqs/block (8 cond1 + 8 cond2).
// Thread (u = tid&127, rg = tid>>7): Whh k-slice [32rg,32rg+32) for unit u's
// 4 gates in 128 VGPRs (zero LDS weight traffic). h-reads are wave-uniform
// LDS broadcasts. Rows in 2 halves of 8 (pS = 64KB). 4 barriers/timestep.
// Epilogue: relu(h@Wc+bc) pairs -> lo, per-block BN1 partials -> gpartial.
// ---------------------------------------------------------------------------
__global__ __launch_bounds__(512, 1) void k_lstm1(
    const float* __restrict__ cond1, const float* __restrict__ cond2,
    const float* __restrict__ WihP, const float* __restrict__ WhhP,
    const float* __restrict__ b1P, const float* __restrict__ Wc,
    const float* __restrict__ bc,
    float* __restrict__ lo_raw, float* __restrict__ gpartial)
{
  __shared__ float4 pS[4][8][128];    // 64KB partial gate sums [rg][row8][u]
  __shared__ float4 hs4[16][32];      // 8KB h state
  __shared__ float  xs[16][132];      // inputs, 10 steps x 13
  __shared__ float4 WihS[13][128];    // 26.6KB Wih permuted
  __shared__ float  rr[16][64];
  __shared__ float  sloc[128];

  const int tid = threadIdx.x, b = blockIdx.x;
  const int u = tid & 127, rg = tid >> 7;

  for (int idx = tid; idx < 16 * 130; idx += 512) {
    int r = idx / 130, d = idx - r * 130;
    xs[r][d] = (r < 8) ? cond1[(8 * b + r) * 130 + d]
                       : cond2[(8 * b + (r - 8)) * 130 + d];
  }
  for (int idx = tid; idx < 13 * 128; idx += 512)
    WihS[idx >> 7][idx & 127] =
        *(const float4*)&WihP[(idx >> 7) * 512 + 4 * (idx & 127)];
  ((float4*)hs4)[tid] = make_float4(0.f, 0.f, 0.f, 0.f);
  if (tid < 128) sloc[tid] = 0.f;

  float4 w[32];
#pragma unroll
  for (int kk = 0; kk < 32; ++kk)
    w[kk] = *(const float4*)&WhhP[(32 * rg + kk) * 512 + 4 * u];
  const float4 b1v = *(const float4*)&b1P[4 * u];
  float creg[4] = {0.f, 0.f, 0.f, 0.f};   // rows 2rg,2rg+1,8+2rg,9+2rg
  __syncthreads();

  for (int t = 0; t < 10; ++t) {
#pragma unroll
    for (int hf = 0; hf < 2; ++hf) {
      const int base = 8 * hf;
#pragma unroll
      for (int row = 0; row < 8; ++row) {
        float4 a = make_float4(0.f, 0.f, 0.f, 0.f);
#pragma unroll
        for (int q = 0; q < 8; ++q) {
          const float4 hv = hs4[base + row][8 * rg + q];  // broadcast
          const float4 w0 = w[4 * q + 0], w1 = w[4 * q + 1];
          const float4 w2 = w[4 * q + 2], w3 = w[4 * q + 3];
          a.x = fmaf(hv.x, w0.x, a.x); a.y = fmaf(hv.x, w0.y, a.y);
          a.z = fmaf(hv.x, w0.z, a.z); a.w = fmaf(hv.x, w0.w, a.w);
          a.x = fmaf(hv.y, w1.x, a.x); a.y = fmaf(hv.y, w1.y, a.y);
          a.z = fmaf(hv.y, w1.z, a.z); a.w = fmaf(hv.y, w1.w, a.w);
          a.x = fmaf(hv.z, w2.x, a.x); a.y = fmaf(hv.z, w2.y, a.y);
          a.z = fmaf(hv.z, w2.z, a.z); a.w = fmaf(hv.z, w2.w, a.w);
          a.x = fmaf(hv.w, w3.x, a.x); a.y = fmaf(hv.w, w3.y, a.y);
          a.z = fmaf(hv.w, w3.z, a.z); a.w = fmaf(hv.w, w3.w, a.w);
        }
        pS[rg][row][u] = a;
      }
      __syncthreads();
      {
        float4 gs[2];
#pragma unroll
        for (int i = 0; i < 2; ++i) {
          const int rh = 2 * rg + i;
          float4 s0 = pS[0][rh][u], s1 = pS[1][rh][u];
          float4 s2 = pS[2][rh][u], s3 = pS[3][rh][u];
          gs[i].x = ((s0.x + s1.x) + (s2.x + s3.x)) + b1v.x;
          gs[i].y = ((s0.y + s1.y) + (s2.y + s3.y)) + b1v.y;
          gs[i].z = ((s0.z + s1.z) + (s2.z + s3.z)) + b1v.z;
          gs[i].w = ((s0.w + s1.w) + (s2.w + s3.w)) + b1v.w;
        }
#pragma unroll
        for (int d = 0; d < 13; ++d) {
          const float4 wv = WihS[d][u];
#pragma unroll
          for (int i = 0; i < 2; ++i) {
            const float xv = xs[base + 2 * rg + i][t * 13 + d];
            gs[i].x = fmaf(xv, wv.x, gs[i].x);
            gs[i].y = fmaf(xv, wv.y, gs[i].y);
            gs[i].z = fmaf(xv, wv.z, gs[i].z);
            gs[i].w = fmaf(xv, wv.w, gs[i].w);
          }
        }
#pragma unroll
        for (int i = 0; i < 2; ++i) {
          const int row = base + 2 * rg + i;
          const int ci = 2 * hf + i;
          float ig = sigf(gs[i].x);
          float fg = sigf(gs[i].y);
          float gg = tanhfast(gs[i].z);
          float og = sigf(gs[i].w);
          float c = fmaf(fg, creg[ci], ig * gg);
          creg[ci] = c;
          ((float*)&hs4[row][0])[u] = og * tanhfast(c);
        }
      }
      __syncthreads();
    }
  }

  // epilogue: rr = relu(h_final @ Wc + bc); 2 rows per thread
  {
    const int oc = tid & 63, r8 = tid >> 6;
    const float* h0 = (const float*)&hs4[2 * r8][0];
    const float* h1 = (const float*)&hs4[2 * r8 + 1][0];
    float a0 = bc[oc], a1 = a0;
    for (int k = 0; k < 128; ++k) {
      float wcv = Wc[k * 64 + oc];
      a0 = fmaf(h0[k], wcv, a0);
      a1 = fmaf(h1[k], wcv, a1);
    }
    rr[2 * r8][oc] = fmaxf(a0, 0.f);
    rr[2 * r8 + 1][oc] = fmaxf(a1, 0.f);
  }
  __syncthreads();
  {
    const int j = tid >> 6, oc = tid & 63;
    float lo = 0.5f * (rr[j][oc] + rr[j + 8][oc]);
    lo_raw[(8 * b + j) * 64 + oc] = lo;
    atomicAdd(&sloc[oc], lo);
    atomicAdd(&sloc[64 + oc], lo * lo);
  }
  __syncthreads();
  if (tid < 128) gpartial[tid * 256 + b] = sloc[tid];
}

// ---------------------------------------------------------------------------
// helper: BN1 av/bv from gpartial (redundant per block)
// ---------------------------------------------------------------------------
__device__ __forceinline__ void bn1_scales(
    const float* __restrict__ gpartial, const float* __restrict__ g1,
    const float* __restrict__ be1, float* sS, float* av, float* bv)
{
  const int tid = threadIdx.x;
  if (tid < 128) {
    const float4* gp = (const float4*)(gpartial + tid * 256);
    float s = 0.f;
    for (int i = 0; i < 64; ++i) {
      float4 v = gp[i];
      s += (v.x + v.y) + (v.z + v.w);
    }
    sS[tid] = s;
  }
  __syncthreads();
  if (tid < 64) {
    float m = sS[tid] * (1.0f / 2048.0f);
    float var = sS[64 + tid] * (1.0f / 2048.0f) - m * m;
    float rstd = rsqrtf(var + 1e-5f);
    float gg = g1[tid];
    av[tid] = rstd * gg;
    bv[tid] = be1[tid] - m * rstd * gg;
  }
  __syncthreads();
}

__device__ __forceinline__ float feat(
    int l, int n, int f, const float* __restrict__ ops,
    const float* __restrict__ extra, const float* __restrict__ card,
    const float* __restrict__ lo_raw, const float* av, const float* bv)
{
  int g = l * 128 + n;
  if (f < 15) return ops[g * 15 + f];
  if (f < 22) return extra[g * 7 + (f - 15)];
  if (f < 24) return card[g * 2 + (f - 22)];
  int j = f - 24;
  return lo_raw[g * 64 + j] * av[j] + bv[j];
}

// ---------------------------------------------------------------------------
// K_mid: blocks 0..63: LSTM2 single step (h0=c0=0) -> hidA/cidA.
//        block 64: base_all[t][k].
// ---------------------------------------------------------------------------
__global__ __launch_bounds__(256) void k_mid(
    const float* __restrict__ ops, const float* __restrict__ extra,
    const float* __restrict__ card, const float* __restrict__ lo_raw,
    const float* __restrict__ gpartial, const float* __restrict__ g1,
    const float* __restrict__ be1, const float* __restrict__ Wih2,
    const float* __restrict__ b2, const float* __restrict__ Win,
    const float* __restrict__ binb, float* __restrict__ hidA,
    float* __restrict__ cidA, float* __restrict__ base_all)
{
  __shared__ float sS[128], av[64], bv[64];
  const int tid = threadIdx.x, bx = blockIdx.x;
  bn1_scales(gpartial, g1, be1, sS, av, bv);

  if (bx < 64) {
    const int idx = bx * 256 + tid;
    const int n = idx >> 7, k = idx & 127;
    float ai = b2[k];
    float ag = b2[256 + k];
    float ao = b2[384 + k];
    for (int f = 0; f < 88; ++f) {
      float xv = feat(15, n, f, ops, extra, card, lo_raw, av, bv);
      ai = fmaf(xv, Wih2[f * 512 + k], ai);
      ag = fmaf(xv, Wih2[f * 512 + 256 + k], ag);
      ao = fmaf(xv, Wih2[f * 512 + 384 + k], ao);
    }
    float c0 = sigf(ai) * tanhfast(ag);
    float h0 = sigf(ao) * tanhfast(c0);
    hidA[idx] = h0;
    cidA[idx] = c0;
  } else {
    for (int idx = tid; idx < 15 * 128; idx += 256) {
      int t = idx >> 7, k = idx & 127;
      float a = binb[k];
      for (int f = 0; f < 88; ++f)
        a = fmaf(feat(t, 0, f, ops, extra, card, lo_raw, av, bv),
                 Win[f * 128 + k], a);
      base_all[idx] = a;
    }
  }
}

// ---------------------------------------------------------------------------
// K_tree: one TreeLSTM level, a=0 slice only (verified round 3). grid 128 =
// 16 k-blocks x 8 n-blocks, 256 threads.
// ---------------------------------------------------------------------------
__global__ __launch_bounds__(256, 1) void k_tree(
    const int* __restrict__ mapping, const float* __restrict__ WT,
    const float* __restrict__ base_all, const float* __restrict__ blh,
    const float* __restrict__ brh, const float* __restrict__ hid_c,
    const float* __restrict__ cid_c, float* __restrict__ hid_n,
    float* __restrict__ cid_n, int t)
{
  __shared__ float wS[10][8][132];
  __shared__ float rowS[32][132];
  __shared__ float pS[10][132];
  const int tid = threadIdx.x, bx = blockIdx.x;
  const int k0 = (bx & 15) * 8, n0 = (bx >> 4) * 16;

  for (int idx = tid; idx < 10 * 8 * 128; idx += 256) {
    int h = idx & 127, kp = (idx >> 7) & 7, sg = idx >> 10;
    wS[sg][kp][h] = WT[sg * 16384 + (k0 + kp) * 128 + h];
  }
  for (int idx = tid; idx < 4096; idx += 256) {
    int row = idx >> 7, h = idx & 127;
    int np_ = row >> 1, side = row & 1;
    int j = mapping[(t * 128 + n0 + np_) * 2 + side];
    rowS[row][h] = (j > 0) ? hid_c[(j - 1) * 128 + h] : 0.0f;
  }
  __syncthreads();

  {
    const int pr = tid >> 1, side = tid & 1;
    const int np_ = pr >> 3, kp = pr & 7;
    const int rrow = np_ * 2 + side;
    float acc[5] = {0.f, 0.f, 0.f, 0.f, 0.f};
    for (int h = 0; h < 128; h += 8) {
      float4 r0 = *(const float4*)&rowS[rrow][h];
      float4 r1 = *(const float4*)&rowS[rrow][h + 4];
#pragma unroll
      for (int g = 0; g < 5; ++g) {
        float4 w0 = *(const float4*)&wS[side * 5 + g][kp][h];
        float4 w1 = *(const float4*)&wS[side * 5 + g][kp][h + 4];
        acc[g] = fmaf(r0.x, w0.x, acc[g]);
        acc[g] = fmaf(r0.y, w0.y, acc[g]);
        acc[g] = fmaf(r0.z, w0.z, acc[g]);
        acc[g] = fmaf(r0.w, w0.w, acc[g]);
        acc[g] = fmaf(r1.x, w1.x, acc[g]);
        acc[g] = fmaf(r1.y, w1.y, acc[g]);
        acc[g] = fmaf(r1.z, w1.z, acc[g]);
        acc[g] = fmaf(r1.w, w1.w, acc[g]);
      }
    }
#pragma unroll
    for (int g = 0; g < 5; ++g) pS[side * 5 + g][pr] = acc[g];
  }
  __syncthreads();
  if (tid < 128) {
    const int np_ = tid >> 3, kp = tid & 7;
    const int n = n0 + np_, k = k0 + kp;
    const float base = base_all[t * 128 + k];
    float pre[5];
#pragma unroll
    for (int g = 0; g < 5; ++g)
      pre[g] = pS[g][tid] + pS[5 + g][tid] + base +
               blh[g * 128 + k] + brh[g * 128 + k];
    int jl = mapping[(t * 128 + n) * 2 + 0];
    int jr = mapping[(t * 128 + n) * 2 + 1];
    float lc = (jl > 0) ? cid_c[(jl - 1) * 128 + k] : 0.0f;
    float rc = (jr > 0) ? cid_c[(jr - 1) * 128 + k] : 0.0f;
    float i_ = sigf(pre[0]);
    float lf = sigf(pre[1]);
    float rf = sigf(pre[2]);
    float u_ = tanhfast(pre[3]);
    float o_ = sigf(pre[4]);
    float c = i_ * u_ + lf * lc + rf * rc;
    hid_n[n * 128 + k] = o_ * tanhfast(c);
    cid_n[n * 128 + k] = c;
  }
}

// ---------------------------------------------------------------------------
// K_head: BN2 -> relu(@Wt1) -> BN3 -> relu(@Wt2) -> sigmoid(@Wo). One block,
// 512 threads. f32 output.
// ---------------------------------------------------------------------------
__global__ __launch_bounds__(512) void k_head(
    const float* __restrict__ hid, const float* __restrict__ g2,
    const float* __restrict__ be2, const float* __restrict__ Wt1,
    const float* __restrict__ bt1, const float* __restrict__ g3,
    const float* __restrict__ be3, const float* __restrict__ Wt2,
    const float* __restrict__ bt2, const float* __restrict__ Wo,
    const float* __restrict__ bo, float* __restrict__ dout)
{
  __shared__ __align__(16) unsigned char pool[32768 + 16384];
  __hip_bfloat16 (*t1s)[128] = (__hip_bfloat16(*)[128])pool;          // 32KB
  __hip_bfloat16 (*t2s)[64]  = (__hip_bfloat16(*)[64])(pool + 32768); // 16KB
  float (*t4s)[64] = (float(*)[64])pool;      // reuses t1 space
  __shared__ float red[8][128];
  __shared__ float av[128], bv[128];
  const int tid = threadIdx.x;

  {
    int k = tid & 127, q = tid >> 7;  // q in [0,4)
    float s = 0.f, s2 = 0.f;
    for (int r = q * 32; r < q * 32 + 32; ++r) {
      float v = hid[r * 128 + k];
      s += v; s2 += v * v;
    }
    red[q][k] = s;
    red[4 + q][k] = s2;
  }
  __syncthreads();
  if (tid < 128) {
    float s = red[0][tid] + red[1][tid] + red[2][tid] + red[3][tid];
    float s2 = red[4][tid] + red[5][tid] + red[6][tid] + red[7][tid];
    float m = s * (1.0f / 128.0f);
    float var = s2 * (1.0f / 128.0f) - m * m;
    float rstd = rsqrtf(var + 1e-5f);
    float gg = g2[tid];
    av[tid] = rstd * gg;
    bv[tid] = be2[tid] - m * rstd * gg;
  }
  __syncthreads();
  for (int idx = tid; idx < 16384; idx += 512) {
    int n = idx >> 7, k = idx & 127;
    t1s[n][k] = __float2bfloat16(hid[idx] * av[k] + bv[k]);
  }
  __syncthreads();
  {
    const int j = tid & 63, ng = tid >> 6;
    float a[16];
#pragma unroll
    for (int r = 0; r < 16; ++r) a[r] = bt1[j];
    for (int k8 = 0; k8 < 128; k8 += 8) {
      float wv[8];
#pragma unroll
      for (int q = 0; q < 8; ++q) wv[q] = Wt1[(k8 + q) * 64 + j];
#pragma unroll
      for (int r = 0; r < 16; ++r) {
        const __hip_bfloat16* row = &t1s[ng * 16 + r][k8];
#pragma unroll
        for (int q = 0; q < 8; ++q)
          a[r] = fmaf(__bfloat162float(row[q]), wv[q], a[r]);
      }
    }
#pragma unroll
    for (int r = 0; r < 16; ++r)
      t2s[ng * 16 + r][j] = __float2bfloat16(fmaxf(a[r], 0.0f));
  }
  __syncthreads();
  {
    int j = tid & 63, q = tid >> 6;  // q in [0,8)
    float s = 0.f, s2 = 0.f;
    for (int r = q * 16; r < q * 16 + 16; ++r) {
      float v = __bfloat162float(t2s[r][j]);
      s += v; s2 += v * v;
    }
    red[q][j] = s;
    red[q][64 + j] = s2;
  }
  __syncthreads();
  if (tid < 64) {
    float s = 0.f, s2 = 0.f;
#pragma unroll
    for (int q = 0; q < 8; ++q) { s += red[q][tid]; s2 += red[q][64 + tid]; }
    float m = s * (1.0f / 128.0f);
    float var = s2 * (1.0f / 128.0f) - m * m;
    float rstd = rsqrtf(var + 1e-5f);
    float gg = g3[tid];
    av[tid] = rstd * gg;
    bv[tid] = be3[tid] - m * rstd * gg;
  }
  __syncthreads();
  {
    const int j2 = tid & 63, ng = tid >> 6;
    float a[16];
#pragma unroll
    for (int r = 0; r < 16; ++r) a[r] = bt2[j2];
    for (int jj = 0; jj < 64; ++jj) {
      float w = Wt2[jj * 64 + j2];
      float aj = av[jj], bj = bv[jj];
#pragma unroll
      for (int r = 0; r < 16; ++r) {
        float x = __bfloat162float(t2s[ng * 16 + r][jj]) * aj + bj;
        a[r] = fmaf(x, w, a[r]);
      }
    }
    __syncthreads();
#pragma unroll
    for (int r = 0; r < 16; ++r) t4s[ng * 16 + r][j2] = fmaxf(a[r], 0.0f);
  }
  __syncthreads();
  if (tid < 128) {
    float a = bo[0];
    for (int j = 0; j < 64; ++j) a = fmaf(t4s[tid][j], Wo[j], a);
    dout[tid] = sigf(a);
  }
}

// ---------------------------------------------------------------------------
extern "C" void kernel_launch(void* const* d_in, const int* in_sizes, int n_in,
                              void* d_out, int out_size, void* d_ws,
                              size_t ws_size, hipStream_t stream)
{
  (void)in_sizes; (void)n_in; (void)out_size; (void)ws_size;
  const float* ops   = (const float*)d_in[0];
  const float* extra = (const float*)d_in[1];
  const float* card  = (const float*)d_in[2];
  const float* cond1 = (const float*)d_in[3];
  const float* cond2 = (const float*)d_in[4];
  const int* mapping = (const int*)d_in[5];
  const float* Wih1 = (const float*)d_in[6];
  const float* Whh1 = (const float*)d_in[7];
  const float* b1   = (const float*)d_in[8];
  const float* Wc   = (const float*)d_in[9];
  const float* bc   = (const float*)d_in[10];
  const float* g1   = (const float*)d_in[11];
  const float* be1  = (const float*)d_in[12];
  const float* Wih2 = (const float*)d_in[13];
  // d_in[14] = Whh2: unused (h0 = 0 in the single-step LSTM2)
  const float* b2   = (const float*)d_in[15];
  const float* Win  = (const float*)d_in[16];
  const float* binb = (const float*)d_in[17];
  const float* Wlh  = (const float*)d_in[18];
  const float* blh  = (const float*)d_in[19];
  const float* Wrh  = (const float*)d_in[20];
  const float* brh  = (const float*)d_in[21];
  const float* g2   = (const float*)d_in[22];
  const float* be2  = (const float*)d_in[23];
  const float* Wt1  = (const float*)d_in[24];
  const float* bt1  = (const float*)d_in[25];
  const float* g3   = (const float*)d_in[26];
  const float* be3  = (const float*)d_in[27];
  const float* Wt2  = (const float*)d_in[28];
  const float* bt2  = (const float*)d_in[29];
  const float* Wo   = (const float*)d_in[30];
  const float* bo   = (const float*)d_in[31];

  char* ws = (char*)d_ws;
  float* WhhP     = (float*)(ws + 0);        // 128x512 f32 = 256KB
  float* WihP     = (float*)(ws + 262144);   // 13x512 f32
  float* b1P      = (float*)(ws + 288768);   // 512 f32
  float* gpartial = (float*)(ws + 290816);   // 128x256 f32 = 128KB
  float* lo_raw   = (float*)(ws + 421888);   // 2048x64 f32
  float* base_all = (float*)(ws + 946176);   // 15x128 f32
  float* WT       = (float*)(ws + 953856);   // 10x128x128 f32
  float* hidA     = (float*)(ws + 1609216);  // 128x128 f32 x4
  float* hidB     = hidA + 16384;
  float* cidA     = hidB + 16384;
  float* cidB     = cidA + 16384;

  k_pre<<<dim3(43), dim3(256), 0, stream>>>(
      Whh1, Wih1, b1, Wlh, Wrh, WhhP, WihP, b1P, WT);
  k_lstm1<<<dim3(256), dim3(512), 0, stream>>>(
      cond1, cond2, WihP, WhhP, b1P, Wc, bc, lo_raw, gpartial);
  k_mid<<<dim3(65), dim3(256), 0, stream>>>(
      ops, extra, card, lo_raw, gpartial, g1, be1, Wih2, b2, Win, binb,
      hidA, cidA, base_all);

  float* hc[2] = {hidA, hidB};
  float* cc[2] = {cidA, cidB};
  for (int s = 0; s < 15; ++s) {
    int t = 14 - s;
    int cur = s & 1, nxt = cur ^ 1;
    k_tree<<<dim3(128), dim3(256), 0, stream>>>(
        mapping, WT, base_all, blh, brh,
        hc[cur], cc[cur], hc[nxt], cc[nxt], t);
  }
  // 15 steps (odd): final state in buffer 1
  k_head<<<dim3(1), dim3(512), 0, stream>>>(
      hc[1], g2, be2, Wt1, bt1, g3, be3, Wt2, bt2, Wo, bo,
      (float*)d_out);
}

// Round 8
// 445.258 us; speedup vs baseline: 2.1366x; 1.2654x over previous
//
#include <hip/hip_runtime.h>
#include <hip/hip_bf16.h>

__device__ __forceinline__ float sigf(float x) {
  return __fdividef(1.0f, 1.0f + __expf(-x));
}
__device__ __forceinline__ float tanhfast(float x) {
  float e = __expf(2.0f * x);
  return 1.0f - __fdividef(2.0f, e + 1.0f);
}

// ---------------------------------------------------------------------------
// K_pre: permuted weights + transposed tree weights.
//  WhhP[k][u*4+g] = Whh1[k][g*128+u]; WihP[d][u*4+g]; b1P[u*4+g];
//  WT[m][k][h] = (m<5?Wlh:Wrh)[m%5][h][k]
// ---------------------------------------------------------------------------
__global__ __launch_bounds__(256) void k_pre(
    const float* __restrict__ Whh1, const float* __restrict__ Wih1,
    const float* __restrict__ b1, const float* __restrict__ Wlh,
    const float* __restrict__ Wrh,
    float* __restrict__ WhhP, float* __restrict__ WihP,
    float* __restrict__ b1P, float* __restrict__ WT)
{
  const int bx = blockIdx.x, tid = threadIdx.x;
  if (bx < 32) {
    for (int i = 0; i < 8; ++i) {
      int dst = bx * 2048 + i * 256 + tid;
      int g = dst & 3, u = (dst >> 2) & 127, k = dst >> 9;
      WhhP[dst] = Whh1[k * 512 + g * 128 + u];
    }
  } else if (bx == 32) {
    for (int idx = tid; idx < 13 * 512; idx += 256) {
      int g = idx & 3, u = (idx >> 2) & 127, d = idx >> 9;
      WihP[idx] = Wih1[d * 512 + g * 128 + u];
    }
    for (int idx = tid; idx < 512; idx += 256)
      b1P[idx] = b1[(idx & 3) * 128 + (idx >> 2)];
  } else {
    __shared__ float tile[32][33];
    const int m = bx - 33;                 // 0..9 = side*5+g
    const int side = m / 5, g = m - side * 5;
    const float* src = (side ? Wrh : Wlh) + g * 16384;
    float* dst = WT + m * 16384;
    const int i = tid >> 5, jj = tid & 31;
    for (int tt = 0; tt < 16; ++tt) {
      const int ti = tt >> 2, tj = tt & 3;
#pragma unroll
      for (int q = 0; q < 4; ++q)
        tile[i + q * 8][jj] = src[(ti * 32 + i + q * 8) * 128 + tj * 32 + jj];
      __syncthreads();
#pragma unroll
      for (int q = 0; q < 4; ++q)
        dst[(tj * 32 + i + q * 8) * 128 + ti * 32 + jj] = tile[jj][i + q * 8];
      __syncthreads();
    }
  }
}

// ---------------------------------------------------------------------------
// K1: LSTM1, 256 blocks x 512 threads, 16 seqs/block (8 cond1 + 8 cond2).
// Thread (u = tid&127, rg = tid>>7): Whh k-slice [32rg,32rg+32) for unit u's
// 4 gates in 128 VGPRs (zero LDS weight traffic). h-reads are wave-uniform
// LDS broadcasts. Rows in 2 halves of 8 (pS = 64KB). 4 barriers/timestep.
// Epilogue: relu(h@Wc+bc) pairs -> lo, per-block BN1 partials -> gpartial.
// ---------------------------------------------------------------------------
__global__ __launch_bounds__(512, 1) void k_lstm1(
    const float* __restrict__ cond1, const float* __restrict__ cond2,
    const float* __restrict__ WihP, const float* __restrict__ WhhP,
    const float* __restrict__ b1P, const float* __restrict__ Wc,
    const float* __restrict__ bc,
    float* __restrict__ lo_raw, float* __restrict__ gpartial)
{
  __shared__ float4 pS[4][8][128];    // 64KB partial gate sums [rg][row8][u]
  __shared__ float4 hs4[16][32];      // 8KB h state
  __shared__ float  xs[16][132];      // inputs, 10 steps x 13
  __shared__ float4 WihS[13][128];    // 26.6KB Wih permuted
  __shared__ float  rr[16][64];
  __shared__ float  sloc[128];

  const int tid = threadIdx.x, b = blockIdx.x;
  const int u = tid & 127, rg = tid >> 7;

  for (int idx = tid; idx < 16 * 130; idx += 512) {
    int r = idx / 130, d = idx - r * 130;
    xs[r][d] = (r < 8) ? cond1[(8 * b + r) * 130 + d]
                       : cond2[(8 * b + (r - 8)) * 130 + d];
  }
  for (int idx = tid; idx < 13 * 128; idx += 512)
    WihS[idx >> 7][idx & 127] =
        *(const float4*)&WihP[(idx >> 7) * 512 + 4 * (idx & 127)];
  ((float4*)hs4)[tid] = make_float4(0.f, 0.f, 0.f, 0.f);
  if (tid < 128) sloc[tid] = 0.f;

  float4 w[32];
#pragma unroll
  for (int kk = 0; kk < 32; ++kk)
    w[kk] = *(const float4*)&WhhP[(32 * rg + kk) * 512 + 4 * u];
  const float4 b1v = *(const float4*)&b1P[4 * u];
  float creg[4] = {0.f, 0.f, 0.f, 0.f};   // rows 2rg,2rg+1,8+2rg,9+2rg
  __syncthreads();

  for (int t = 0; t < 10; ++t) {
#pragma unroll
    for (int hf = 0; hf < 2; ++hf) {
      const int base = 8 * hf;
#pragma unroll
      for (int row = 0; row < 8; ++row) {
        float4 a = make_float4(0.f, 0.f, 0.f, 0.f);
#pragma unroll
        for (int q = 0; q < 8; ++q) {
          const float4 hv = hs4[base + row][8 * rg + q];  // broadcast
          const float4 w0 = w[4 * q + 0], w1 = w[4 * q + 1];
          const float4 w2 = w[4 * q + 2], w3 = w[4 * q + 3];
          a.x = fmaf(hv.x, w0.x, a.x); a.y = fmaf(hv.x, w0.y, a.y);
          a.z = fmaf(hv.x, w0.z, a.z); a.w = fmaf(hv.x, w0.w, a.w);
          a.x = fmaf(hv.y, w1.x, a.x); a.y = fmaf(hv.y, w1.y, a.y);
          a.z = fmaf(hv.y, w1.z, a.z); a.w = fmaf(hv.y, w1.w, a.w);
          a.x = fmaf(hv.z, w2.x, a.x); a.y = fmaf(hv.z, w2.y, a.y);
          a.z = fmaf(hv.z, w2.z, a.z); a.w = fmaf(hv.z, w2.w, a.w);
          a.x = fmaf(hv.w, w3.x, a.x); a.y = fmaf(hv.w, w3.y, a.y);
          a.z = fmaf(hv.w, w3.z, a.z); a.w = fmaf(hv.w, w3.w, a.w);
        }
        pS[rg][row][u] = a;
      }
      __syncthreads();
      {
        float4 gs[2];
#pragma unroll
        for (int i = 0; i < 2; ++i) {
          const int rh = 2 * rg + i;
          float4 s0 = pS[0][rh][u], s1 = pS[1][rh][u];
          float4 s2 = pS[2][rh][u], s3 = pS[3][rh][u];
          gs[i].x = ((s0.x + s1.x) + (s2.x + s3.x)) + b1v.x;
          gs[i].y = ((s0.y + s1.y) + (s2.y + s3.y)) + b1v.y;
          gs[i].z = ((s0.z + s1.z) + (s2.z + s3.z)) + b1v.z;
          gs[i].w = ((s0.w + s1.w) + (s2.w + s3.w)) + b1v.w;
        }
#pragma unroll
        for (int d = 0; d < 13; ++d) {
          const float4 wv = WihS[d][u];
#pragma unroll
          for (int i = 0; i < 2; ++i) {
            const float xv = xs[base + 2 * rg + i][t * 13 + d];
            gs[i].x = fmaf(xv, wv.x, gs[i].x);
            gs[i].y = fmaf(xv, wv.y, gs[i].y);
            gs[i].z = fmaf(xv, wv.z, gs[i].z);
            gs[i].w = fmaf(xv, wv.w, gs[i].w);
          }
        }
#pragma unroll
        for (int i = 0; i < 2; ++i) {
          const int row = base + 2 * rg + i;
          const int ci = 2 * hf + i;
          float ig = sigf(gs[i].x);
          float fg = sigf(gs[i].y);
          float gg = tanhfast(gs[i].z);
          float og = sigf(gs[i].w);
          float c = fmaf(fg, creg[ci], ig * gg);
          creg[ci] = c;
          ((float*)&hs4[row][0])[u] = og * tanhfast(c);
        }
      }
      __syncthreads();
    }
  }

  // epilogue: rr = relu(h_final @ Wc + bc); 2 rows per thread
  {
    const int oc = tid & 63, r8 = tid >> 6;
    const float* h0 = (const float*)&hs4[2 * r8][0];
    const float* h1 = (const float*)&hs4[2 * r8 + 1][0];
    float a0 = bc[oc], a1 = a0;
    for (int k = 0; k < 128; ++k) {
      float wcv = Wc[k * 64 + oc];
      a0 = fmaf(h0[k], wcv, a0);
      a1 = fmaf(h1[k], wcv, a1);
    }
    rr[2 * r8][oc] = fmaxf(a0, 0.f);
    rr[2 * r8 + 1][oc] = fmaxf(a1, 0.f);
  }
  __syncthreads();
  {
    const int j = tid >> 6, oc = tid & 63;
    float lo = 0.5f * (rr[j][oc] + rr[j + 8][oc]);
    lo_raw[(8 * b + j) * 64 + oc] = lo;
    atomicAdd(&sloc[oc], lo);
    atomicAdd(&sloc[64 + oc], lo * lo);
  }
  __syncthreads();
  if (tid < 128) gpartial[tid * 256 + b] = sloc[tid];
}

// ---------------------------------------------------------------------------
// helper: BN1 av/bv from gpartial (redundant per block)
// ---------------------------------------------------------------------------
__device__ __forceinline__ void bn1_scales(
    const float* __restrict__ gpartial, const float* __restrict__ g1,
    const float* __restrict__ be1, float* sS, float* av, float* bv)
{
  const int tid = threadIdx.x;
  if (tid < 128) {
    const float4* gp = (const float4*)(gpartial + tid * 256);
    float s = 0.f;
    for (int i = 0; i < 64; ++i) {
      float4 v = gp[i];
      s += (v.x + v.y) + (v.z + v.w);
    }
    sS[tid] = s;
  }
  __syncthreads();
  if (tid < 64) {
    float m = sS[tid] * (1.0f / 2048.0f);
    float var = sS[64 + tid] * (1.0f / 2048.0f) - m * m;
    float rstd = rsqrtf(var + 1e-5f);
    float gg = g1[tid];
    av[tid] = rstd * gg;
    bv[tid] = be1[tid] - m * rstd * gg;
  }
  __syncthreads();
}

__device__ __forceinline__ float feat(
    int l, int n, int f, const float* __restrict__ ops,
    const float* __restrict__ extra, const float* __restrict__ card,
    const float* __restrict__ lo_raw, const float* av, const float* bv)
{
  int g = l * 128 + n;
  if (f < 15) return ops[g * 15 + f];
  if (f < 22) return extra[g * 7 + (f - 15)];
  if (f < 24) return card[g * 2 + (f - 22)];
  int j = f - 24;
  return lo_raw[g * 64 + j] * av[j] + bv[j];
}

// ---------------------------------------------------------------------------
// K_mid: blocks 0..63: LSTM2 step for n = {2bx, 2bx+1}: X staged in LDS,
// unrolled coalesced dots (h0=c0=0 -> only i,g,o gates).
// blocks 64..78: base_all level t=bx-64: X staged, 1 dot per thread.
// ---------------------------------------------------------------------------
__global__ __launch_bounds__(256) void k_mid(
    const float* __restrict__ ops, const float* __restrict__ extra,
    const float* __restrict__ card, const float* __restrict__ lo_raw,
    const float* __restrict__ gpartial, const float* __restrict__ g1,
    const float* __restrict__ be1, const float* __restrict__ Wih2,
    const float* __restrict__ b2, const float* __restrict__ Win,
    const float* __restrict__ binb, float* __restrict__ hidA,
    float* __restrict__ cidA, float* __restrict__ base_all)
{
  __shared__ float sS[128], av[64], bv[64];
  __shared__ float X[2][88];
  const int tid = threadIdx.x, bx = blockIdx.x;
  bn1_scales(gpartial, g1, be1, sS, av, bv);

  if (bx < 64) {
    // stage X rows n = 2bx, 2bx+1 (level 15)
    if (tid < 176) {
      int r = tid / 88, f = tid - r * 88;
      X[r][f] = feat(15, 2 * bx + r, f, ops, extra, card, lo_raw, av, bv);
    }
    __syncthreads();
    const int nl = tid >> 7, k = tid & 127;
    const float* Xr = X[nl];
    float ai = b2[k];
    float ag = b2[256 + k];
    float ao = b2[384 + k];
#pragma unroll 8
    for (int f = 0; f < 88; ++f) {
      float xv = Xr[f];
      ai = fmaf(xv, Wih2[f * 512 + k], ai);
      ag = fmaf(xv, Wih2[f * 512 + 256 + k], ag);
      ao = fmaf(xv, Wih2[f * 512 + 384 + k], ao);
    }
    float c0 = sigf(ai) * tanhfast(ag);
    float h0 = sigf(ao) * tanhfast(c0);
    const int idx = (2 * bx + nl) * 128 + k;
    hidA[idx] = h0;
    cidA[idx] = c0;
  } else {
    const int t = bx - 64;                 // 0..14
    if (tid < 88)
      X[0][tid] = feat(t, 0, tid, ops, extra, card, lo_raw, av, bv);
    __syncthreads();
    if (tid < 128) {
      float a = binb[tid];
#pragma unroll 8
      for (int f = 0; f < 88; ++f)
        a = fmaf(X[0][f], Win[f * 128 + tid], a);
      base_all[t * 128 + tid] = a;
    }
  }
}

// ---------------------------------------------------------------------------
// K_tree: one TreeLSTM level, a=0 slice. grid 64 = 16 k-tiles(8) x 4
// n-tiles(32), 512 threads. Same math/accumulation order as the verified
// 128-block version; n-tile doubled to halve per-level weight staging.
// ---------------------------------------------------------------------------
__global__ __launch_bounds__(512, 1) void k_tree(
    const int* __restrict__ mapping, const float* __restrict__ WT,
    const float* __restrict__ base_all, const float* __restrict__ blh,
    const float* __restrict__ brh, const float* __restrict__ hid_c,
    const float* __restrict__ cid_c, float* __restrict__ hid_n,
    float* __restrict__ cid_n, int t)
{
  __shared__ float wS[10][8][132];   // 42.2KB (side*5+g, k', h)
  __shared__ float rowS[64][132];    // 33.8KB (n'*2+side, h)
  __shared__ float pS[10][264];      // 10.6KB partials [sg][pr]
  const int tid = threadIdx.x, bx = blockIdx.x;
  const int k0 = (bx & 15) * 8, n0 = (bx >> 4) * 32;

  for (int idx = tid; idx < 10 * 8 * 128; idx += 512) {
    int h = idx & 127, kp = (idx >> 7) & 7, sg = idx >> 10;
    wS[sg][kp][h] = WT[sg * 16384 + (k0 + kp) * 128 + h];
  }
  for (int idx = tid; idx < 64 * 128; idx += 512) {
    int row = idx >> 7, h = idx & 127;
    int np_ = row >> 1, side = row & 1;
    int j = mapping[(t * 128 + n0 + np_) * 2 + side];
    rowS[row][h] = (j > 0) ? hid_c[(j - 1) * 128 + h] : 0.0f;
  }
  __syncthreads();

  {
    const int pr = tid >> 1, side = tid & 1;   // pr in [0,256)
    const int np_ = pr >> 3, kp = pr & 7;
    const int rrow = np_ * 2 + side;
    float acc[5] = {0.f, 0.f, 0.f, 0.f, 0.f};
    for (int h = 0; h < 128; h += 8) {
      float4 r0 = *(const float4*)&rowS[rrow][h];
      float4 r1 = *(const float4*)&rowS[rrow][h + 4];
#pragma unroll
      for (int g = 0; g < 5; ++g) {
        float4 w0 = *(const float4*)&wS[side * 5 + g][kp][h];
        float4 w1 = *(const float4*)&wS[side * 5 + g][kp][h + 4];
        acc[g] = fmaf(r0.x, w0.x, acc[g]);
        acc[g] = fmaf(r0.y, w0.y, acc[g]);
        acc[g] = fmaf(r0.z, w0.z, acc[g]);
        acc[g] = fmaf(r0.w, w0.w, acc[g]);
        acc[g] = fmaf(r1.x, w1.x, acc[g]);
        acc[g] = fmaf(r1.y, w1.y, acc[g]);
        acc[g] = fmaf(r1.z, w1.z, acc[g]);
        acc[g] = fmaf(r1.w, w1.w, acc[g]);
      }
    }
#pragma unroll
    for (int g = 0; g < 5; ++g) pS[side * 5 + g][pr] = acc[g];
  }
  __syncthreads();
  if (tid < 256) {
    const int np_ = tid >> 3, kp = tid & 7;
    const int n = n0 + np_, k = k0 + kp;
    const float base = base_all[t * 128 + k];
    float pre[5];
#pragma unroll
    for (int g = 0; g < 5; ++g)
      pre[g] = pS[g][tid] + pS[5 + g][tid] + base +
               blh[g * 128 + k] + brh[g * 128 + k];
    int jl = mapping[(t * 128 + n) * 2 + 0];
    int jr = mapping[(t * 128 + n) * 2 + 1];
    float lc = (jl > 0) ? cid_c[(jl - 1) * 128 + k] : 0.0f;
    float rc = (jr > 0) ? cid_c[(jr - 1) * 128 + k] : 0.0f;
    float i_ = sigf(pre[0]);
    float lf = sigf(pre[1]);
    float rf = sigf(pre[2]);
    float u_ = tanhfast(pre[3]);
    float o_ = sigf(pre[4]);
    float c = i_ * u_ + lf * lc + rf * rc;
    hid_n[n * 128 + k] = o_ * tanhfast(c);
    cid_n[n * 128 + k] = c;
  }
}

// ---------------------------------------------------------------------------
// K_head: BN2 -> relu(@Wt1) -> BN3 -> relu(@Wt2) -> sigmoid(@Wo). One block,
// 512 threads. f32 output.
// ---------------------------------------------------------------------------
__global__ __launch_bounds__(512) void k_head(
    const float* __restrict__ hid, const float* __restrict__ g2,
    const float* __restrict__ be2, const float* __restrict__ Wt1,
    const float* __restrict__ bt1, const float* __restrict__ g3,
    const float* __restrict__ be3, const float* __restrict__ Wt2,
    const float* __restrict__ bt2, const float* __restrict__ Wo,
    const float* __restrict__ bo, float* __restrict__ dout)
{
  __shared__ __align__(16) unsigned char pool[32768 + 16384];
  __hip_bfloat16 (*t1s)[128] = (__hip_bfloat16(*)[128])pool;          // 32KB
  __hip_bfloat16 (*t2s)[64]  = (__hip_bfloat16(*)[64])(pool + 32768); // 16KB
  float (*t4s)[64] = (float(*)[64])pool;      // reuses t1 space
  __shared__ float red[8][128];
  __shared__ float av[128], bv[128];
  const int tid = threadIdx.x;

  {
    int k = tid & 127, q = tid >> 7;  // q in [0,4)
    float s = 0.f, s2 = 0.f;
    for (int r = q * 32; r < q * 32 + 32; ++r) {
      float v = hid[r * 128 + k];
      s += v; s2 += v * v;
    }
    red[q][k] = s;
    red[4 + q][k] = s2;
  }
  __syncthreads();
  if (tid < 128) {
    float s = red[0][tid] + red[1][tid] + red[2][tid] + red[3][tid];
    float s2 = red[4][tid] + red[5][tid] + red[6][tid] + red[7][tid];
    float m = s * (1.0f / 128.0f);
    float var = s2 * (1.0f / 128.0f) - m * m;
    float rstd = rsqrtf(var + 1e-5f);
    float gg = g2[tid];
    av[tid] = rstd * gg;
    bv[tid] = be2[tid] - m * rstd * gg;
  }
  __syncthreads();
  for (int idx = tid; idx < 16384; idx += 512) {
    int n = idx >> 7, k = idx & 127;
    t1s[n][k] = __float2bfloat16(hid[idx] * av[k] + bv[k]);
  }
  __syncthreads();
  {
    const int j = tid & 63, ng = tid >> 6;
    float a[16];
#pragma unroll
    for (int r = 0; r < 16; ++r) a[r] = bt1[j];
    for (int k8 = 0; k8 < 128; k8 += 8) {
      float wv[8];
#pragma unroll
      for (int q = 0; q < 8; ++q) wv[q] = Wt1[(k8 + q) * 64 + j];
#pragma unroll
      for (int r = 0; r < 16; ++r) {
        const __hip_bfloat16* row = &t1s[ng * 16 + r][k8];
#pragma unroll
        for (int q = 0; q < 8; ++q)
          a[r] = fmaf(__bfloat162float(row[q]), wv[q], a[r]);
      }
    }
#pragma unroll
    for (int r = 0; r < 16; ++r)
      t2s[ng * 16 + r][j] = __float2bfloat16(fmaxf(a[r], 0.0f));
  }
  __syncthreads();
  {
    int j = tid & 63, q = tid >> 6;  // q in [0,8)
    float s = 0.f, s2 = 0.f;
    for (int r = q * 16; r < q * 16 + 16; ++r) {
      float v = __bfloat162float(t2s[r][j]);
      s += v; s2 += v * v;
    }
    red[q][j] = s;
    red[q][64 + j] = s2;
  }
  __syncthreads();
  if (tid < 64) {
    float s = 0.f, s2 = 0.f;
#pragma unroll
    for (int q = 0; q < 8; ++q) { s += red[q][tid]; s2 += red[q][64 + tid]; }
    float m = s * (1.0f / 128.0f);
    float var = s2 * (1.0f / 128.0f) - m * m;
    float rstd = rsqrtf(var + 1e-5f);
    float gg = g3[tid];
    av[tid] = rstd * gg;
    bv[tid] = be3[tid] - m * rstd * gg;
  }
  __syncthreads();
  {
    const int j2 = tid & 63, ng = tid >> 6;
    float a[16];
#pragma unroll
    for (int r = 0; r < 16; ++r) a[r] = bt2[j2];
    for (int jj = 0; jj < 64; ++jj) {
      float w = Wt2[jj * 64 + j2];
      float aj = av[jj], bj = bv[jj];
#pragma unroll
      for (int r = 0; r < 16; ++r) {
        float x = __bfloat162float(t2s[ng * 16 + r][jj]) * aj + bj;
        a[r] = fmaf(x, w, a[r]);
      }
    }
    __syncthreads();
#pragma unroll
    for (int r = 0; r < 16; ++r) t4s[ng * 16 + r][j2] = fmaxf(a[r], 0.0f);
  }
  __syncthreads();
  if (tid < 128) {
    float a = bo[0];
    for (int j = 0; j < 64; ++j) a = fmaf(t4s[tid][j], Wo[j], a);
    dout[tid] = sigf(a);
  }
}

// ---------------------------------------------------------------------------
extern "C" void kernel_launch(void* const* d_in, const int* in_sizes, int n_in,
                              void* d_out, int out_size, void* d_ws,
                              size_t ws_size, hipStream_t stream)
{
  (void)in_sizes; (void)n_in; (void)out_size; (void)ws_size;
  const float* ops   = (const float*)d_in[0];
  const float* extra = (const float*)d_in[1];
  const float* card  = (const float*)d_in[2];
  const float* cond1 = (const float*)d_in[3];
  const float* cond2 = (const float*)d_in[4];
  const int* mapping = (const int*)d_in[5];
  const float* Wih1 = (const float*)d_in[6];
  const float* Whh1 = (const float*)d_in[7];
  const float* b1   = (const float*)d_in[8];
  const float* Wc   = (const float*)d_in[9];
  const float* bc   = (const float*)d_in[10];
  const float* g1   = (const float*)d_in[11];
  const float* be1  = (const float*)d_in[12];
  const float* Wih2 = (const float*)d_in[13];
  // d_in[14] = Whh2: unused (h0 = 0 in the single-step LSTM2)
  const float* b2   = (const float*)d_in[15];
  const float* Win  = (const float*)d_in[16];
  const float* binb = (const float*)d_in[17];
  const float* Wlh  = (const float*)d_in[18];
  const float* blh  = (const float*)d_in[19];
  const float* Wrh  = (const float*)d_in[20];
  const float* brh  = (const float*)d_in[21];
  const float* g2   = (const float*)d_in[22];
  const float* be2  = (const float*)d_in[23];
  const float* Wt1  = (const float*)d_in[24];
  const float* bt1  = (const float*)d_in[25];
  const float* g3   = (const float*)d_in[26];
  const float* be3  = (const float*)d_in[27];
  const float* Wt2  = (const float*)d_in[28];
  const float* bt2  = (const float*)d_in[29];
  const float* Wo   = (const float*)d_in[30];
  const float* bo   = (const float*)d_in[31];

  char* ws = (char*)d_ws;
  float* WhhP     = (float*)(ws + 0);        // 128x512 f32 = 256KB
  float* WihP     = (float*)(ws + 262144);   // 13x512 f32
  float* b1P      = (float*)(ws + 288768);   // 512 f32
  float* gpartial = (float*)(ws + 290816);   // 128x256 f32 = 128KB
  float* lo_raw   = (float*)(ws + 421888);   // 2048x64 f32
  float* base_all = (float*)(ws + 946176);   // 15x128 f32
  float* WT       = (float*)(ws + 953856);   // 10x128x128 f32
  float* hidA     = (float*)(ws + 1609216);  // 128x128 f32 x4
  float* hidB     = hidA + 16384;
  float* cidA     = hidB + 16384;
  float* cidB     = cidA + 16384;

  k_pre<<<dim3(43), dim3(256), 0, stream>>>(
      Whh1, Wih1, b1, Wlh, Wrh, WhhP, WihP, b1P, WT);
  k_lstm1<<<dim3(256), dim3(512), 0, stream>>>(
      cond1, cond2, WihP, WhhP, b1P, Wc, bc, lo_raw, gpartial);
  k_mid<<<dim3(79), dim3(256), 0, stream>>>(
      ops, extra, card, lo_raw, gpartial, g1, be1, Wih2, b2, Win, binb,
      hidA, cidA, base_all);

  float* hc[2] = {hidA, hidB};
  float* cc[2] = {cidA, cidB};
  for (int s = 0; s < 15; ++s) {
    int t = 14 - s;
    int cur = s & 1, nxt = cur ^ 1;
    k_tree<<<dim3(64), dim3(512), 0, stream>>>(
        mapping, WT, base_all, blh, brh,
        hc[cur], cc[cur], hc[nxt], cc[nxt], t);
  }
  // 15 steps (odd): final state in buffer 1
  k_head<<<dim3(1), dim3(512), 0, stream>>>(
      hc[1], g2, be2, Wt1, bt1, g3, be3, Wt2, bt2, Wo, bo,
      (float*)d_out);
}

// Round 10
// 394.041 us; speedup vs baseline: 2.4143x; 1.1300x over previous
//
#include <hip/hip_runtime.h>
#include <hip/hip_bf16.h>

typedef __attribute__((ext_vector_type(8))) short short8v;
typedef __attribute__((ext_vector_type(4))) short short4v;
typedef __attribute__((ext_vector_type(4))) float f32x4;

__device__ __forceinline__ float sigf(float x) {
  return __fdividef(1.0f, 1.0f + __expf(-x));
}
__device__ __forceinline__ float tanhfast(float x) {
  float e = __expf(2.0f * x);
  return 1.0f - __fdividef(2.0f, e + 1.0f);
}
__device__ __forceinline__ unsigned short rne_bf16(float x) {
  unsigned u = __float_as_uint(x);
  return (unsigned short)((u + 0x7fffu + ((u >> 16) & 1u)) >> 16);
}
__device__ __forceinline__ float bf2f(unsigned short s) {
  return __uint_as_float(((unsigned)s) << 16);
}

// ---------------------------------------------------------------------------
// K_pre: bx<40: Bft = MFMA B-fragments of W_aug = [Whh1;Wih1;0] (160x512),
// hi/lo bf16, fragment-packed: element (p,q,ct,l,e):
//   kk = 32q + (l>>4)*8 + e, col = 16ct + (l&15).
// bx 40..49: WT[m][k][h] = (m<5?Wlh:Wrh)[m%5][h][k] (tree weights).
// ---------------------------------------------------------------------------
__global__ __launch_bounds__(256) void k_pre(
    const float* __restrict__ Whh1, const float* __restrict__ Wih1,
    const float* __restrict__ Wlh, const float* __restrict__ Wrh,
    unsigned short* __restrict__ Bft, float* __restrict__ WT)
{
  const int bx = blockIdx.x, tid = threadIdx.x;
  if (bx < 40) {
    for (int i = 0; i < 16; ++i) {
      int idx = (bx * 256 + tid) * 16 + i;       // [0, 163840)
      int p = (idx >= 81920) ? 1 : 0;
      int r = idx - p * 81920;
      int q = r >> 14;
      int rem = r & 16383;
      int ct = rem >> 9, l = (rem >> 3) & 63, e = rem & 7;
      int kk = 32 * q + ((l >> 4) << 3) + e;
      int col = (ct << 4) + (l & 15);
      float x = 0.f;
      if (kk < 128) x = Whh1[kk * 512 + col];
      else if (kk < 141) x = Wih1[(kk - 128) * 512 + col];
      unsigned short hi = rne_bf16(x);
      Bft[idx] = p ? rne_bf16(x - bf2f(hi)) : hi;
    }
  } else {
    __shared__ float tile[32][33];
    const int m = bx - 40;                 // 0..9 = side*5+g
    const int side = m / 5, g = m - side * 5;
    const float* src = (side ? Wrh : Wlh) + g * 16384;
    float* dst = WT + m * 16384;
    const int i = tid >> 5, jj = tid & 31;
    for (int tt = 0; tt < 16; ++tt) {
      const int ti = tt >> 2, tj = tt & 3;
#pragma unroll
      for (int q = 0; q < 4; ++q)
        tile[i + q * 8][jj] = src[(ti * 32 + i + q * 8) * 128 + tj * 32 + jj];
      __syncthreads();
#pragma unroll
      for (int q = 0; q < 4; ++q)
        dst[(tj * 32 + i + q * 8) * 128 + ti * 32 + jj] = tile[jj][i + q * 8];
      __syncthreads();
    }
  }
}

// ---------------------------------------------------------------------------
// K1: LSTM1 via MFMA (hi/lo bf16 split, fp32-accurate). 256 blocks x 512 thr,
// 16 seqs/block. Per t: gates(16x512) = A(16x160)@B(160x512)+b via
// mfma_f32_16x16x32_bf16: wave w owns col-tiles 4w..4w+3; B-frags in VGPRs
// (loaded once); A-frags (h hi/lo + x chunk) rebuilt in LDS by gate phase.
// 2 barriers/t. Epilogue: relu(h@Wc+bc) -> lo pairs -> BN1 partials.
// ---------------------------------------------------------------------------
__global__ __launch_bounds__(512, 1) void k_lstm1(
    const float* __restrict__ cond1, const float* __restrict__ cond2,
    const unsigned short* __restrict__ Bft, const float* __restrict__ b1,
    const float* __restrict__ Wc, const float* __restrict__ bc,
    float* __restrict__ lo_raw, float* __restrict__ gpartial)
{
  __shared__ __align__(16) unsigned short AftS[2][5][64][8];  // 10KB
  __shared__ float preS[16][516];   // 33KB gate pre-activations
  __shared__ float xs[16][132];     // inputs 10t x 13
  __shared__ float hsF[16][132];    // h state f32 (epilogue)
  __shared__ float rr[16][64];
  __shared__ float sloc[128];

  const int tid = threadIdx.x, b = blockIdx.x;
  const int wid = tid >> 6, lane = tid & 63;

  for (int idx = tid; idx < 16 * 130; idx += 512) {
    int r = idx / 130, d = idx - r * 130;
    xs[r][d] = (r < 8) ? cond1[(8 * b + r) * 130 + d]
                       : cond2[(8 * b + (r - 8)) * 130 + d];
  }
  // zero AftS: 5120 u16 = 2560 u32 (round-9 bug: 5120 u32 = 2x overflow)
  for (int idx = tid; idx < 2560; idx += 512) ((unsigned*)AftS)[idx] = 0u;
  if (tid < 128) sloc[tid] = 0.f;

  // B fragments: wave w -> col-tiles ct = 4w..4w+3, all 5 k-chunks, hi+lo.
  short8v Bh[5][4], Bl[5][4];
  {
    const short8v* gB = (const short8v*)Bft;
#pragma unroll
    for (int q = 0; q < 5; ++q)
#pragma unroll
      for (int j = 0; j < 4; ++j) {
        int ct = 4 * wid + j;
        Bh[q][j] = gB[(q * 32 + ct) * 64 + lane];
        Bl[q][j] = gB[((5 + q) * 32 + ct) * 64 + lane];
      }
  }
  float biasv[4];
#pragma unroll
  for (int j = 0; j < 4; ++j) biasv[j] = b1[(4 * wid + j) * 16 + (lane & 15)];

  const int grow = tid >> 5;       // gate-phase row [0,16)
  const int guu = (tid & 31) * 4;  // gate-phase unit base
  float creg[4] = {0.f, 0.f, 0.f, 0.f};

  __syncthreads();   // xs + zeroed AftS visible
  // x chunk (kk=128..140) for t=0
  if (tid < 256) {
    int p = tid >> 7, s = tid & 127, row = s & 15, grp = s >> 4;
    {
      float v = xs[row][grp];
      unsigned short hi = rne_bf16(v);
      AftS[p][4][row][grp] = p ? rne_bf16(v - bf2f(hi)) : hi;
    }
    if (grp < 5) {
      float v = xs[row][8 + grp];
      unsigned short hi = rne_bf16(v);
      AftS[p][4][16 + row][grp] = p ? rne_bf16(v - bf2f(hi)) : hi;
    }
  }
  __syncthreads();

  for (int t = 0; t < 10; ++t) {
    // ---- MFMA phase: pre = [h;x] @ W_aug + b ----
    f32x4 acc[4];
#pragma unroll
    for (int j = 0; j < 4; ++j)
      acc[j] = (f32x4){biasv[j], biasv[j], biasv[j], biasv[j]};
#pragma unroll
    for (int q = 0; q < 5; ++q) {
      short8v ah = *(const short8v*)&AftS[0][q][lane][0];
      short8v al = *(const short8v*)&AftS[1][q][lane][0];
#pragma unroll
      for (int j = 0; j < 4; ++j) {
        acc[j] = __builtin_amdgcn_mfma_f32_16x16x32_bf16(al, Bh[q][j],
                                                         acc[j], 0, 0, 0);
        acc[j] = __builtin_amdgcn_mfma_f32_16x16x32_bf16(ah, Bl[q][j],
                                                         acc[j], 0, 0, 0);
        acc[j] = __builtin_amdgcn_mfma_f32_16x16x32_bf16(ah, Bh[q][j],
                                                         acc[j], 0, 0, 0);
      }
    }
    // D -> preS: col = 16ct + (lane&15), row = (lane>>4)*4 + r
#pragma unroll
    for (int j = 0; j < 4; ++j) {
      int c = (4 * wid + j) * 16 + (lane & 15);
      int r0 = (lane >> 4) * 4;
#pragma unroll
      for (int r = 0; r < 4; ++r) preS[r0 + r][c] = acc[j][r];
    }
    __syncthreads();
    // ---- gate phase: thread = (grow, units guu..guu+3) ----
    {
      float4 pi = *(const float4*)&preS[grow][0 * 128 + guu];
      float4 pf = *(const float4*)&preS[grow][1 * 128 + guu];
      float4 pg = *(const float4*)&preS[grow][2 * 128 + guu];
      float4 po = *(const float4*)&preS[grow][3 * 128 + guu];
      float hv[4];
#pragma unroll
      for (int i2 = 0; i2 < 4; ++i2) {
        float ig = sigf(((const float*)&pi)[i2]);
        float fg = sigf(((const float*)&pf)[i2]);
        float gg = tanhfast(((const float*)&pg)[i2]);
        float og = sigf(((const float*)&po)[i2]);
        float c = fmaf(fg, creg[i2], ig * gg);
        creg[i2] = c;
        hv[i2] = og * tanhfast(c);
      }
      *(float4*)&hsF[grow][guu] = make_float4(hv[0], hv[1], hv[2], hv[3]);
      // h -> A-fragments (hi/lo): chunk = guu>>5, lane = grow+16*((guu>>3)&3)
      unsigned short h0 = rne_bf16(hv[0]), h1 = rne_bf16(hv[1]);
      unsigned short h2 = rne_bf16(hv[2]), h3 = rne_bf16(hv[3]);
      short4v hiv = (short4v){(short)h0, (short)h1, (short)h2, (short)h3};
      short4v lov = (short4v){(short)rne_bf16(hv[0] - bf2f(h0)),
                              (short)rne_bf16(hv[1] - bf2f(h1)),
                              (short)rne_bf16(hv[2] - bf2f(h2)),
                              (short)rne_bf16(hv[3] - bf2f(h3))};
      int chunk = guu >> 5;
      int lA = grow + 16 * ((guu >> 3) & 3);
      int e0 = guu & 7;
      *(short4v*)&AftS[0][chunk][lA][e0] = hiv;
      *(short4v*)&AftS[1][chunk][lA][e0] = lov;
    }
    // x chunk for t+1
    if (t < 9 && tid < 256) {
      int p = tid >> 7, s = tid & 127, row = s & 15, grp = s >> 4;
      {
        float v = xs[row][(t + 1) * 13 + grp];
        unsigned short hi = rne_bf16(v);
        AftS[p][4][row][grp] = p ? rne_bf16(v - bf2f(hi)) : hi;
      }
      if (grp < 5) {
        float v = xs[row][(t + 1) * 13 + 8 + grp];
        unsigned short hi = rne_bf16(v);
        AftS[p][4][16 + row][grp] = p ? rne_bf16(v - bf2f(hi)) : hi;
      }
    }
    __syncthreads();
  }

  // epilogue: rr = relu(h_final @ Wc + bc); 2 rows per thread
  {
    const int oc = tid & 63, r8 = tid >> 6;
    const float* h0p = &hsF[2 * r8][0];
    const float* h1p = &hsF[2 * r8 + 1][0];
    float a0 = bc[oc], a1 = a0;
    for (int k = 0; k < 128; ++k) {
      float wcv = Wc[k * 64 + oc];
      a0 = fmaf(h0p[k], wcv, a0);
      a1 = fmaf(h1p[k], wcv, a1);
    }
    rr[2 * r8][oc] = fmaxf(a0, 0.f);
    rr[2 * r8 + 1][oc] = fmaxf(a1, 0.f);
  }
  __syncthreads();
  {
    const int j = tid >> 6, oc = tid & 63;
    float lo = 0.5f * (rr[j][oc] + rr[j + 8][oc]);
    lo_raw[(8 * b + j) * 64 + oc] = lo;
    atomicAdd(&sloc[oc], lo);
    atomicAdd(&sloc[64 + oc], lo * lo);
  }
  __syncthreads();
  if (tid < 128) gpartial[tid * 256 + b] = sloc[tid];
}

// ---------------------------------------------------------------------------
// helper: BN1 av/bv from gpartial (redundant per block)
// ---------------------------------------------------------------------------
__device__ __forceinline__ void bn1_scales(
    const float* __restrict__ gpartial, const float* __restrict__ g1,
    const float* __restrict__ be1, float* sS, float* av, float* bv)
{
  const int tid = threadIdx.x;
  if (tid < 128) {
    const float4* gp = (const float4*)(gpartial + tid * 256);
    float s = 0.f;
    for (int i = 0; i < 64; ++i) {
      float4 v = gp[i];
      s += (v.x + v.y) + (v.z + v.w);
    }
    sS[tid] = s;
  }
  __syncthreads();
  if (tid < 64) {
    float m = sS[tid] * (1.0f / 2048.0f);
    float var = sS[64 + tid] * (1.0f / 2048.0f) - m * m;
    float rstd = rsqrtf(var + 1e-5f);
    float gg = g1[tid];
    av[tid] = rstd * gg;
    bv[tid] = be1[tid] - m * rstd * gg;
  }
  __syncthreads();
}

__device__ __forceinline__ float feat(
    int l, int n, int f, const float* __restrict__ ops,
    const float* __restrict__ extra, const float* __restrict__ card,
    const float* __restrict__ lo_raw, const float* av, const float* bv)
{
  int g = l * 128 + n;
  if (f < 15) return ops[g * 15 + f];
  if (f < 22) return extra[g * 7 + (f - 15)];
  if (f < 24) return card[g * 2 + (f - 22)];
  int j = f - 24;
  return lo_raw[g * 64 + j] * av[j] + bv[j];
}

// ---------------------------------------------------------------------------
// K_mid: blocks 0..63: LSTM2 step for n = {2bx, 2bx+1} (h0=c0=0).
// blocks 64..78: base_all level t = bx-64.
// ---------------------------------------------------------------------------
__global__ __launch_bounds__(256) void k_mid(
    const float* __restrict__ ops, const float* __restrict__ extra,
    const float* __restrict__ card, const float* __restrict__ lo_raw,
    const float* __restrict__ gpartial, const float* __restrict__ g1,
    const float* __restrict__ be1, const float* __restrict__ Wih2,
    const float* __restrict__ b2, const float* __restrict__ Win,
    const float* __restrict__ binb, float* __restrict__ hidA,
    float* __restrict__ cidA, float* __restrict__ base_all)
{
  __shared__ float sS[128], av[64], bv[64];
  __shared__ float X[2][88];
  const int tid = threadIdx.x, bx = blockIdx.x;
  bn1_scales(gpartial, g1, be1, sS, av, bv);

  if (bx < 64) {
    if (tid < 176) {
      int r = tid / 88, f = tid - r * 88;
      X[r][f] = feat(15, 2 * bx + r, f, ops, extra, card, lo_raw, av, bv);
    }
    __syncthreads();
    const int nl = tid >> 7, k = tid & 127;
    const float* Xr = X[nl];
    float ai = b2[k];
    float ag = b2[256 + k];
    float ao = b2[384 + k];
#pragma unroll 8
    for (int f = 0; f < 88; ++f) {
      float xv = Xr[f];
      ai = fmaf(xv, Wih2[f * 512 + k], ai);
      ag = fmaf(xv, Wih2[f * 512 + 256 + k], ag);
      ao = fmaf(xv, Wih2[f * 512 + 384 + k], ao);
    }
    float c0 = sigf(ai) * tanhfast(ag);
    float h0 = sigf(ao) * tanhfast(c0);
    const int idx = (2 * bx + nl) * 128 + k;
    hidA[idx] = h0;
    cidA[idx] = c0;
  } else {
    const int t = bx - 64;
    if (tid < 88)
      X[0][tid] = feat(t, 0, tid, ops, extra, card, lo_raw, av, bv);
    __syncthreads();
    if (tid < 128) {
      float a = binb[tid];
#pragma unroll 8
      for (int f = 0; f < 88; ++f)
        a = fmaf(X[0][f], Win[f * 128 + tid], a);
      base_all[t * 128 + tid] = a;
    }
  }
}

// ---------------------------------------------------------------------------
// K_tree v3: one level. grid 64 = 16 k-tiles(8) x 4 n-tiles(32), 512 thr.
// Wave = kp (wave-uniform -> wS reads are 2-addr broadcasts); lane = row
// (np*2+side; rowS lane-major). Side-sum via shfl_xor(1). One barrier.
// ---------------------------------------------------------------------------
__global__ __launch_bounds__(512, 1) void k_tree(
    const int* __restrict__ mapping, const float* __restrict__ WT,
    const float* __restrict__ base_all, const float* __restrict__ blh,
    const float* __restrict__ brh, const float* __restrict__ hid_c,
    const float* __restrict__ cid_c, float* __restrict__ hid_n,
    float* __restrict__ cid_n, int t)
{
  __shared__ float wS[10][8][132];   // 42.2KB
  __shared__ float rowS[64][132];    // 33.8KB
  const int tid = threadIdx.x, bx = blockIdx.x;
  const int k0 = (bx & 15) * 8, n0 = (bx >> 4) * 32;

  for (int idx = tid; idx < 10240; idx += 512) {
    int h = idx & 127, kp = (idx >> 7) & 7, sg = idx >> 10;
    wS[sg][kp][h] = WT[sg * 16384 + (k0 + kp) * 128 + h];
  }
  for (int idx = tid; idx < 8192; idx += 512) {
    int row = idx >> 7, h = idx & 127;
    int np_ = row >> 1, side = row & 1;
    int j = mapping[(t * 128 + n0 + np_) * 2 + side];
    rowS[row][h] = (j > 0) ? hid_c[(j - 1) * 128 + h] : 0.0f;
  }
  __syncthreads();

  const int wid = tid >> 6, lane = tid & 63;
  const int kp = wid, k = k0 + kp;
  const int np_ = lane >> 1, side = lane & 1, n = n0 + np_;

  float acc[5] = {0.f, 0.f, 0.f, 0.f, 0.f};
  const float* rp = &rowS[lane][0];
  for (int h = 0; h < 128; h += 8) {
    float4 r0 = *(const float4*)&rp[h];
    float4 r1 = *(const float4*)&rp[h + 4];
#pragma unroll
    for (int g = 0; g < 5; ++g) {
      float4 w0 = *(const float4*)&wS[side * 5 + g][kp][h];
      float4 w1 = *(const float4*)&wS[side * 5 + g][kp][h + 4];
      acc[g] = fmaf(r0.x, w0.x, acc[g]);
      acc[g] = fmaf(r0.y, w0.y, acc[g]);
      acc[g] = fmaf(r0.z, w0.z, acc[g]);
      acc[g] = fmaf(r0.w, w0.w, acc[g]);
      acc[g] = fmaf(r1.x, w1.x, acc[g]);
      acc[g] = fmaf(r1.y, w1.y, acc[g]);
      acc[g] = fmaf(r1.z, w1.z, acc[g]);
      acc[g] = fmaf(r1.w, w1.w, acc[g]);
    }
  }
#pragma unroll
  for (int g = 0; g < 5; ++g) acc[g] += __shfl_xor(acc[g], 1);

  const float base = base_all[t * 128 + k];
  float pre[5];
#pragma unroll
  for (int g = 0; g < 5; ++g)
    pre[g] = acc[g] + base + blh[g * 128 + k] + brh[g * 128 + k];
  int jl = mapping[(t * 128 + n) * 2 + 0];
  int jr = mapping[(t * 128 + n) * 2 + 1];
  float lc = (jl > 0) ? cid_c[(jl - 1) * 128 + k] : 0.0f;
  float rc = (jr > 0) ? cid_c[(jr - 1) * 128 + k] : 0.0f;
  float i_ = sigf(pre[0]);
  float lf = sigf(pre[1]);
  float rf = sigf(pre[2]);
  float u_ = tanhfast(pre[3]);
  float o_ = sigf(pre[4]);
  float c = i_ * u_ + lf * lc + rf * rc;
  if (side == 0) {
    hid_n[n * 128 + k] = o_ * tanhfast(c);
    cid_n[n * 128 + k] = c;
  }
}

// ---------------------------------------------------------------------------
// K_head: BN2 -> relu(@Wt1) -> BN3 -> relu(@Wt2) -> sigmoid(@Wo). One block,
// 512 threads. f32 output.
// ---------------------------------------------------------------------------
__global__ __launch_bounds__(512) void k_head(
    const float* __restrict__ hid, const float* __restrict__ g2,
    const float* __restrict__ be2, const float* __restrict__ Wt1,
    const float* __restrict__ bt1, const float* __restrict__ g3,
    const float* __restrict__ be3, const float* __restrict__ Wt2,
    const float* __restrict__ bt2, const float* __restrict__ Wo,
    const float* __restrict__ bo, float* __restrict__ dout)
{
  __shared__ __align__(16) unsigned char pool[32768 + 16384];
  __hip_bfloat16 (*t1s)[128] = (__hip_bfloat16(*)[128])pool;
  __hip_bfloat16 (*t2s)[64]  = (__hip_bfloat16(*)[64])(pool + 32768);
  float (*t4s)[64] = (float(*)[64])pool;
  __shared__ float red[8][128];
  __shared__ float av[128], bv[128];
  const int tid = threadIdx.x;

  {
    int k = tid & 127, q = tid >> 7;
    float s = 0.f, s2 = 0.f;
    for (int r = q * 32; r < q * 32 + 32; ++r) {
      float v = hid[r * 128 + k];
      s += v; s2 += v * v;
    }
    red[q][k] = s;
    red[4 + q][k] = s2;
  }
  __syncthreads();
  if (tid < 128) {
    float s = red[0][tid] + red[1][tid] + red[2][tid] + red[3][tid];
    float s2 = red[4][tid] + red[5][tid] + red[6][tid] + red[7][tid];
    float m = s * (1.0f / 128.0f);
    float var = s2 * (1.0f / 128.0f) - m * m;
    float rstd = rsqrtf(var + 1e-5f);
    float gg = g2[tid];
    av[tid] = rstd * gg;
    bv[tid] = be2[tid] - m * rstd * gg;
  }
  __syncthreads();
  for (int idx = tid; idx < 16384; idx += 512) {
    int n = idx >> 7, k = idx & 127;
    t1s[n][k] = __float2bfloat16(hid[idx] * av[k] + bv[k]);
  }
  __syncthreads();
  {
    const int j = tid & 63, ng = tid >> 6;
    float a[16];
#pragma unroll
    for (int r = 0; r < 16; ++r) a[r] = bt1[j];
    for (int k8 = 0; k8 < 128; k8 += 8) {
      float wv[8];
#pragma unroll
      for (int q = 0; q < 8; ++q) wv[q] = Wt1[(k8 + q) * 64 + j];
#pragma unroll
      for (int r = 0; r < 16; ++r) {
        const __hip_bfloat16* row = &t1s[ng * 16 + r][k8];
#pragma unroll
        for (int q = 0; q < 8; ++q)
          a[r] = fmaf(__bfloat162float(row[q]), wv[q], a[r]);
      }
    }
#pragma unroll
    for (int r = 0; r < 16; ++r)
      t2s[ng * 16 + r][j] = __float2bfloat16(fmaxf(a[r], 0.0f));
  }
  __syncthreads();
  {
    int j = tid & 63, q = tid >> 6;
    float s = 0.f, s2 = 0.f;
    for (int r = q * 16; r < q * 16 + 16; ++r) {
      float v = __bfloat162float(t2s[r][j]);
      s += v; s2 += v * v;
    }
    red[q][j] = s;
    red[q][64 + j] = s2;
  }
  __syncthreads();
  if (tid < 64) {
    float s = 0.f, s2 = 0.f;
#pragma unroll
    for (int q = 0; q < 8; ++q) { s += red[q][tid]; s2 += red[q][64 + tid]; }
    float m = s * (1.0f / 128.0f);
    float var = s2 * (1.0f / 128.0f) - m * m;
    float rstd = rsqrtf(var + 1e-5f);
    float gg = g3[tid];
    av[tid] = rstd * gg;
    bv[tid] = be3[tid] - m * rstd * gg;
  }
  __syncthreads();
  {
    const int j2 = tid & 63, ng = tid >> 6;
    float a[16];
#pragma unroll
    for (int r = 0; r < 16; ++r) a[r] = bt2[j2];
    for (int jj = 0; jj < 64; ++jj) {
      float w = Wt2[jj * 64 + j2];
      float aj = av[jj], bj = bv[jj];
#pragma unroll
      for (int r = 0; r < 16; ++r) {
        float x = __bfloat162float(t2s[ng * 16 + r][jj]) * aj + bj;
        a[r] = fmaf(x, w, a[r]);
      }
    }
    __syncthreads();
#pragma unroll
    for (int r = 0; r < 16; ++r) t4s[ng * 16 + r][j2] = fmaxf(a[r], 0.0f);
  }
  __syncthreads();
  if (tid < 128) {
    float a = bo[0];
    for (int j = 0; j < 64; ++j) a = fmaf(t4s[tid][j], Wo[j], a);
    dout[tid] = sigf(a);
  }
}

// ---------------------------------------------------------------------------
extern "C" void kernel_launch(void* const* d_in, const int* in_sizes, int n_in,
                              void* d_out, int out_size, void* d_ws,
                              size_t ws_size, hipStream_t stream)
{
  (void)in_sizes; (void)n_in; (void)out_size; (void)ws_size;
  const float* ops   = (const float*)d_in[0];
  const float* extra = (const float*)d_in[1];
  const float* card  = (const float*)d_in[2];
  const float* cond1 = (const float*)d_in[3];
  const float* cond2 = (const float*)d_in[4];
  const int* mapping = (const int*)d_in[5];
  const float* Wih1 = (const float*)d_in[6];
  const float* Whh1 = (const float*)d_in[7];
  const float* b1   = (const float*)d_in[8];
  const float* Wc   = (const float*)d_in[9];
  const float* bc   = (const float*)d_in[10];
  const float* g1   = (const float*)d_in[11];
  const float* be1  = (const float*)d_in[12];
  const float* Wih2 = (const float*)d_in[13];
  // d_in[14] = Whh2: unused (h0 = 0 in the single-step LSTM2)
  const float* b2   = (const float*)d_in[15];
  const float* Win  = (const float*)d_in[16];
  const float* binb = (const float*)d_in[17];
  const float* Wlh  = (const float*)d_in[18];
  const float* blh  = (const float*)d_in[19];
  const float* Wrh  = (const float*)d_in[20];
  const float* brh  = (const float*)d_in[21];
  const float* g2   = (const float*)d_in[22];
  const float* be2  = (const float*)d_in[23];
  const float* Wt1  = (const float*)d_in[24];
  const float* bt1  = (const float*)d_in[25];
  const float* g3   = (const float*)d_in[26];
  const float* be3  = (const float*)d_in[27];
  const float* Wt2  = (const float*)d_in[28];
  const float* bt2  = (const float*)d_in[29];
  const float* Wo   = (const float*)d_in[30];
  const float* bo   = (const float*)d_in[31];

  char* ws = (char*)d_ws;
  unsigned short* Bft = (unsigned short*)(ws + 0);  // 163840 u16 = 320KB
  float* gpartial = (float*)(ws + 327680);   // 128x256 f32 = 128KB
  float* lo_raw   = (float*)(ws + 458752);   // 2048x64 f32 = 512KB
  float* base_all = (float*)(ws + 983040);   // 15x128 f32
  float* WT       = (float*)(ws + 990720);   // 10x128x128 f32 = 640KB
  float* hidA     = (float*)(ws + 1646080);  // 128x128 f32 x4
  float* hidB     = hidA + 16384;
  float* cidA     = hidB + 16384;
  float* cidB     = cidA + 16384;

  k_pre<<<dim3(50), dim3(256), 0, stream>>>(Whh1, Wih1, Wlh, Wrh, Bft, WT);
  k_lstm1<<<dim3(256), dim3(512), 0, stream>>>(
      cond1, cond2, Bft, b1, Wc, bc, lo_raw, gpartial);
  k_mid<<<dim3(79), dim3(256), 0, stream>>>(
      ops, extra, card, lo_raw, gpartial, g1, be1, Wih2, b2, Win, binb,
      hidA, cidA, base_all);

  float* hc[2] = {hidA, hidB};
  float* cc[2] = {cidA, cidB};
  for (int s = 0; s < 15; ++s) {
    int t = 14 - s;
    int cur = s & 1, nxt = cur ^ 1;
    k_tree<<<dim3(64), dim3(512), 0, stream>>>(
        mapping, WT, base_all, blh, brh,
        hc[cur], cc[cur], hc[nxt], cc[nxt], t);
  }
  // 15 steps (odd): final state in buffer 1
  k_head<<<dim3(1), dim3(512), 0, stream>>>(
      hc[1], g2, be2, Wt1, bt1, g3, be3, Wt2, bt2, Wo, bo,
      (float*)d_out);
}